// Round 6
// baseline (701.097 us; speedup 1.0000x reference)
//
#include <hip/hip_runtime.h>
#include <math.h>

// GCN 2-layer. Radix-partition CSR build, XCD-feature-sharded aggregation:
// slice = blockIdx%8 pins each feature slice to one XCD (round-robin dispatch),
// making the gather source L2-resident (3.2MB / 1.6MB per slice).
// out = Anorm( relu(Anorm(x@W1)+b1) @ W2 ) + b2,  Anorm = D^-1/2 (A+I) D^-1/2.
// h1s = dinv*(x@W1); o1 = relu(dinv*(sum h1s)+b1); h2s = dinv*(o1@W2);
// out = dinv*(sum h2s) + b2.   ("sum" includes the self row.)

#define THREADS 256
#define PBLK 256      // partition blocks (hist chunking must match)
#define BSHIFT 8      // bucket = dst >> 8 (256 nodes/bucket)

typedef float f2v __attribute__((ext_vector_type(2)));

__device__ __forceinline__ f2v ld_f2(const float* p) { return *(const f2v*)p; }
__device__ __forceinline__ void nt_store_f2(float* p, f2v v) {
    __builtin_nontemporal_store(v, (f2v*)p);
}
__device__ __forceinline__ int nt_ld_i(const int* p) {
    return __builtin_nontemporal_load(p);
}

// block-local int64-layout detection (consistent across blocks: same data)
__device__ __forceinline__ int detect64_block(const int* __restrict__ idx, int E,
                                              int* s_flag) {
    if (threadIdx.x == 0) *s_flag = 1;
    __syncthreads();
    int n = (E < 1024) ? E : 1024;
    for (int i = threadIdx.x; i < n; i += THREADS)
        if (idx[2 * i + 1] != 0) *s_flag = 0;  // benign race, only 0 written
    __syncthreads();
    return *s_flag;
}

// ---------------- per-block bucket histogram (+ inline detection) ----------------
__global__ __launch_bounds__(THREADS) void k_hist(const int* __restrict__ idx, int E,
                                                  int* __restrict__ bh, int NB) {
    extern __shared__ int lh[];  // NB + 1
    int is64 = detect64_block(idx, E, &lh[NB]);
    for (int t = threadIdx.x; t < NB; t += THREADS) lh[t] = 0;
    __syncthreads();
    int chunk = (E + PBLK - 1) / PBLK;
    int start = blockIdx.x * chunk;
    int end = min(start + chunk, E);
    for (int e = start + threadIdx.x; e < end; e += THREADS) {
        int d = is64 ? idx[2 * E + 2 * e] : idx[E + e];
        atomicAdd(&lh[d >> BSHIFT], 1);
    }
    __syncthreads();
    for (int t = threadIdx.x; t < NB; t += THREADS)
        bh[blockIdx.x * NB + t] = lh[t];
}

// ---------------- meta: colsum + exclusive scan + per-(block,bucket) bases ----------------
__global__ __launch_bounds__(THREADS) void k_meta(const int* __restrict__ bh,
                                                  int* __restrict__ boff,
                                                  int* __restrict__ bbase, int NB) {
    __shared__ int cnt_s[1024];
    for (int b = threadIdx.x; b < NB; b += THREADS) {
        int s = 0;
        for (int k = 0; k < PBLK; ++k) s += bh[k * NB + b];
        cnt_s[b] = s;
    }
    __syncthreads();
    if (threadIdx.x == 0) {
        int run = 0;
        for (int b = 0; b < NB; ++b) {
            int c = cnt_s[b];
            cnt_s[b] = run;
            boff[b] = run;
            run += c;
        }
        boff[NB] = run;  // == E
    }
    __syncthreads();
    for (int b = threadIdx.x; b < NB; b += THREADS) {
        int run = cnt_s[b];
        for (int k = 0; k < PBLK; ++k) {
            int i = k * NB + b;
            bbase[i] = run;
            run += bh[i];
        }
    }
}

// ---------------- partition: packed (ldst<<24)|src into bucket ranges ----------------
// requires src < 2^24 (N = 100K here)
__global__ __launch_bounds__(THREADS) void k_partition(const int* __restrict__ idx, int E,
                                                       const int* __restrict__ bbase,
                                                       unsigned* __restrict__ pairs, int NB) {
    extern __shared__ int sm[];
    int* lbase = sm;        // NB
    int* lcur  = sm + NB;   // NB (+1 for flag)
    int is64 = detect64_block(idx, E, &lcur[NB]);
    for (int t = threadIdx.x; t < NB; t += THREADS) {
        lbase[t] = bbase[blockIdx.x * NB + t];
        lcur[t] = 0;
    }
    __syncthreads();
    int chunk = (E + PBLK - 1) / PBLK;
    int start = blockIdx.x * chunk;
    int end = min(start + chunk, E);
    for (int e = start + threadIdx.x; e < end; e += THREADS) {
        int s = is64 ? idx[2 * e] : idx[e];
        int d = is64 ? idx[2 * E + 2 * e] : idx[E + e];
        int b = d >> BSHIFT;
        int r = atomicAdd(&lcur[b], 1);
        pairs[lbase[b] + r] = (unsigned)s | ((unsigned)(d & 255) << 24);
    }
}

// ---------------- per-bucket counting sort -> csr_src, row_ptr, dinv ----------------
__global__ __launch_bounds__(THREADS) void k_sort(const unsigned* __restrict__ pairs,
                                                  const int* __restrict__ boff,
                                                  int* __restrict__ csr_src,
                                                  int* __restrict__ row_ptr,
                                                  float* __restrict__ dinv, int N, int NB) {
    __shared__ int cnt[256];
    __shared__ int cur[256];
    __shared__ int wsum[4];
    const int b = blockIdx.x, t = threadIdx.x;
    const int start = boff[b], end = boff[b + 1];
    cnt[t] = 0;
    __syncthreads();
    for (int j = start + t; j < end; j += THREADS)
        atomicAdd(&cnt[pairs[j] >> 24], 1);
    __syncthreads();
    int deg = cnt[t];
    int lane = t & 63, w = t >> 6;
    int v = deg;
#pragma unroll
    for (int o = 1; o < 64; o <<= 1) {
        int u = __shfl_up(v, o);
        if (lane >= o) v += u;
    }
    if (lane == 63) wsum[w] = v;
    __syncthreads();
    int wadd = 0;
#pragma unroll
    for (int k = 0; k < 4; ++k) if (k < w) wadd += wsum[k];
    int pos = start + (v - deg) + wadd;
    cur[t] = pos;
    int node = (b << BSHIFT) + t;
    if (node < N) {
        row_ptr[node] = pos;
        dinv[node] = rsqrtf((float)(deg + 1));  // +1 self loop
    }
    if (b == NB - 1 && t == 0) row_ptr[N] = end;
    __syncthreads();
    for (int j = start + t; j < end; j += THREADS) {
        unsigned p = pairs[j];
        int r = atomicAdd(&cur[p >> 24], 1);
        csr_src[r] = (int)(p & 0xFFFFFFu);
    }
}

// ---------------- GEMM1: h1s = dinv[row] * (x @ W1)   [N,128]@[128,64] ----------------
__global__ __launch_bounds__(THREADS) void k_gemm1(const float* __restrict__ x,
                                                   const float* __restrict__ W,
                                                   const float* __restrict__ dinv,
                                                   float* __restrict__ h, int N) {
    __shared__ float xs[64][68];
    __shared__ float ws[64][64];
    const int tid = threadIdx.x;
    const int brow = blockIdx.x * 64;
    const int lane = tid & 63, wv = tid >> 6;
    const int jc = (lane & 15) << 2;
    const int rb = (lane >> 4) + (wv << 2);
    float4 acc[4];
    acc[0] = acc[1] = acc[2] = acc[3] = make_float4(0.f, 0.f, 0.f, 0.f);

    for (int kt = 0; kt < 128; kt += 64) {
        for (int f = tid; f < 64 * 16; f += THREADS) {
            int r = f >> 4, k4 = (f & 15) << 2;
            int row = brow + r;
            float4 v = make_float4(0.f, 0.f, 0.f, 0.f);
            if (row < N) v = *(const float4*)&x[(size_t)row * 128 + kt + k4];
            *(float4*)&xs[r][k4] = v;
        }
        for (int f = tid; f < 64 * 16; f += THREADS) {
            int k = f >> 4, c4 = (f & 15) << 2;
            *(float4*)&ws[k][c4] = *(const float4*)&W[(size_t)(kt + k) * 64 + c4];
        }
        __syncthreads();
#pragma unroll
        for (int k = 0; k < 64; k += 4) {
            float4 a[4], b[4];
#pragma unroll
            for (int i = 0; i < 4; ++i) a[i] = *(const float4*)&xs[rb + (i << 4)][k];
#pragma unroll
            for (int kk = 0; kk < 4; ++kk) b[kk] = *(const float4*)&ws[k + kk][jc];
#pragma unroll
            for (int i = 0; i < 4; ++i) {
                const float* ai = (const float*)&a[i];
#pragma unroll
                for (int kk = 0; kk < 4; ++kk) {
                    float av = ai[kk];
                    acc[i].x += av * b[kk].x;
                    acc[i].y += av * b[kk].y;
                    acc[i].z += av * b[kk].z;
                    acc[i].w += av * b[kk].w;
                }
            }
        }
        __syncthreads();
    }
#pragma unroll
    for (int i = 0; i < 4; ++i) {
        int row = brow + rb + (i << 4);
        if (row < N) {
            float dn = dinv[row];
            acc[i].x *= dn; acc[i].y *= dn; acc[i].z *= dn; acc[i].w *= dn;
            *(float4*)&h[(size_t)row * 64 + jc] = acc[i];
        }
    }
}

// ---------------- layer-1 agg, XCD-sharded: slice = bid%8 (8 floats) ----------------
// wave = node; 16 edge-slots x 4 lanes (float2 each). o1 = relu(dinv*(sum)+b1).
__global__ __launch_bounds__(THREADS) void k_agg1s(const int* __restrict__ row_ptr,
                                                   const int* __restrict__ csr,
                                                   const float* __restrict__ dinv,
                                                   const float* __restrict__ hs,
                                                   const float* __restrict__ b1,
                                                   float* __restrict__ o1, int N) {
    const int slice = blockIdx.x & 7;
    const int fbase = slice << 3;
    const int node = ((blockIdx.x >> 3) << 2) + (threadIdx.x >> 6);
    if (node >= N) return;
    const int lane = threadIdx.x & 63;
    const int es = lane >> 2;        // edge slot 0..15
    const int fo = (lane & 3) << 1;  // feature offset within slice (float2)

    int start = nt_ld_i(&row_ptr[node]);
    int end = nt_ld_i(&row_ptr[node + 1]);
    f2v acc = {0.f, 0.f};
    for (int j = start + es; j < end; j += 16) {
        int s = nt_ld_i(&csr[j]);
        f2v v = ld_f2(&hs[(size_t)s * 64 + fbase + fo]);
        acc += v;
    }
#pragma unroll
    for (int off = 4; off < 64; off <<= 1) {
        acc.x += __shfl_xor(acc.x, off);
        acc.y += __shfl_xor(acc.y, off);
    }
    if (lane < 4) {
        float dn = dinv[node];
        f2v self = ld_f2(&hs[(size_t)node * 64 + fbase + fo]);
        f2v bb = ld_f2(&b1[fbase + fo]);
        f2v r;
        r.x = fmaxf(dn * (acc.x + self.x) + bb.x, 0.f);
        r.y = fmaxf(dn * (acc.y + self.y) + bb.y, 0.f);
        nt_store_f2(&o1[(size_t)node * 64 + fbase + fo], r);
    }
}

// ---------------- GEMM2: h2s = dinv[row] * (o1 @ W2)  [N,64]@[64,32] ----------------
__global__ __launch_bounds__(THREADS) void k_gemm2(const float* __restrict__ a_in,
                                                   const float* __restrict__ W,
                                                   const float* __restrict__ dinv,
                                                   float* __restrict__ h, int N) {
    __shared__ float xs[128][68];
    __shared__ float ws[64][32];
    const int tid = threadIdx.x;
    const int brow = blockIdx.x * 128;
    for (int f = tid; f < 128 * 16; f += THREADS) {
        int r = f >> 4, k4 = (f & 15) << 2;
        int row = brow + r;
        float4 v = make_float4(0.f, 0.f, 0.f, 0.f);
        if (row < N) v = *(const float4*)&a_in[(size_t)row * 64 + k4];
        *(float4*)&xs[r][k4] = v;
    }
    for (int f = tid; f < 64 * 8; f += THREADS) {
        int k = f >> 3, c4 = (f & 7) << 2;
        *(float4*)&ws[k][c4] = *(const float4*)&W[(size_t)k * 32 + c4];
    }
    __syncthreads();
    const int lane = tid & 63, wv = tid >> 6;
    const int jc = (lane & 7) << 2;
    const int rb = (lane >> 3) + (wv << 3);
    float4 acc[4];
    acc[0] = acc[1] = acc[2] = acc[3] = make_float4(0.f, 0.f, 0.f, 0.f);
#pragma unroll
    for (int k = 0; k < 64; k += 4) {
        float4 a[4], b[4];
#pragma unroll
        for (int i = 0; i < 4; ++i) a[i] = *(const float4*)&xs[rb + (i << 5)][k];
#pragma unroll
        for (int kk = 0; kk < 4; ++kk) b[kk] = *(const float4*)&ws[k + kk][jc];
#pragma unroll
        for (int i = 0; i < 4; ++i) {
            const float* ai = (const float*)&a[i];
#pragma unroll
            for (int kk = 0; kk < 4; ++kk) {
                float av = ai[kk];
                acc[i].x += av * b[kk].x;
                acc[i].y += av * b[kk].y;
                acc[i].z += av * b[kk].z;
                acc[i].w += av * b[kk].w;
            }
        }
    }
#pragma unroll
    for (int i = 0; i < 4; ++i) {
        int row = brow + rb + (i << 5);
        if (row < N) {
            float dn = dinv[row];
            acc[i].x *= dn; acc[i].y *= dn; acc[i].z *= dn; acc[i].w *= dn;
            *(float4*)&h[(size_t)row * 32 + jc] = acc[i];
        }
    }
}

// ---------------- layer-2 agg, XCD-sharded: slice = bid%8 (4 floats) ----------------
// wave = node; 32 edge-slots x 2 lanes (float2 each). out = dinv*(sum)+b2.
__global__ __launch_bounds__(THREADS) void k_agg2s(const int* __restrict__ row_ptr,
                                                   const int* __restrict__ csr,
                                                   const float* __restrict__ dinv,
                                                   const float* __restrict__ hs,
                                                   const float* __restrict__ b2,
                                                   float* __restrict__ out, int N) {
    const int slice = blockIdx.x & 7;
    const int fbase = slice << 2;
    const int node = ((blockIdx.x >> 3) << 2) + (threadIdx.x >> 6);
    if (node >= N) return;
    const int lane = threadIdx.x & 63;
    const int es = lane >> 1;        // edge slot 0..31
    const int fo = (lane & 1) << 1;  // float2 offset within 4-feat slice

    int start = nt_ld_i(&row_ptr[node]);
    int end = nt_ld_i(&row_ptr[node + 1]);
    f2v acc = {0.f, 0.f};
    for (int j = start + es; j < end; j += 32) {
        int s = nt_ld_i(&csr[j]);
        f2v v = ld_f2(&hs[(size_t)s * 32 + fbase + fo]);
        acc += v;
    }
#pragma unroll
    for (int off = 2; off < 64; off <<= 1) {
        acc.x += __shfl_xor(acc.x, off);
        acc.y += __shfl_xor(acc.y, off);
    }
    if (lane < 2) {
        float dn = dinv[node];
        f2v self = ld_f2(&hs[(size_t)node * 32 + fbase + fo]);
        f2v bb = ld_f2(&b2[fbase + fo]);
        f2v r;
        r.x = dn * (acc.x + self.x) + bb.x;
        r.y = dn * (acc.y + self.y) + bb.y;
        nt_store_f2(&out[(size_t)node * 32 + fbase + fo], r);
    }
}

extern "C" void kernel_launch(void* const* d_in, const int* in_sizes, int n_in,
                              void* d_out, int out_size, void* d_ws, size_t ws_size,
                              hipStream_t stream) {
    const int N = in_sizes[0] / 128;
    const int E = in_sizes[1] / 2;
    const float* x  = (const float*)d_in[0];
    const int*   ei = (const int*)d_in[1];
    const float* W1 = (const float*)d_in[2];
    const float* b1 = (const float*)d_in[3];
    const float* W2 = (const float*)d_in[4];
    const float* b2 = (const float*)d_in[5];
    float* out = (float*)d_out;

    const int NB = (N + 255) >> BSHIFT;

    // workspace carve. pairs aliases h1s (dead until k_gemm1, which runs after k_sort).
    float* dinv    = (float*)d_ws;                    // N
    float* h1s     = dinv + N;                        // N*64
    float* o1      = h1s + (size_t)N * 64;            // N*64
    float* h2s     = o1 + (size_t)N * 64;             // N*32
    int*   csr_src = (int*)(h2s + (size_t)N * 32);    // E
    int*   row_ptr = csr_src + E;                     // N+1
    int*   bh      = row_ptr + N + 1;                 // PBLK*NB
    int*   bbase   = bh + (size_t)PBLK * NB;          // PBLK*NB
    int*   boff    = bbase + (size_t)PBLK * NB;       // NB+1
    unsigned* pairs = (unsigned*)h1s;                 // E (aliased)

    k_hist<<<PBLK, THREADS, (NB + 1) * 4, stream>>>(ei, E, bh, NB);
    k_meta<<<1, THREADS, 0, stream>>>(bh, boff, bbase, NB);
    k_partition<<<PBLK, THREADS, (2 * NB + 1) * 4, stream>>>(ei, E, bbase, pairs, NB);
    k_sort<<<NB, THREADS, 0, stream>>>(pairs, boff, csr_src, row_ptr, dinv, N, NB);

    k_gemm1<<<(N + 63) / 64, THREADS, 0, stream>>>(x, W1, dinv, h1s, N);

    const int nodeblk = (N + 3) / 4;  // 4 node-waves per block
    k_agg1s<<<nodeblk * 8, THREADS, 0, stream>>>(row_ptr, csr_src, dinv, h1s, b1, o1, N);
    k_gemm2<<<(N + 127) / 128, THREADS, 0, stream>>>(o1, W2, dinv, h2s, N);
    k_agg2s<<<nodeblk * 8, THREADS, 0, stream>>>(row_ptr, csr_src, dinv, h2s, b2, out, N);
}

// Round 7
// 235.178 us; speedup vs baseline: 2.9811x; 2.9811x over previous
//
#include <hip/hip_runtime.h>
#include <math.h>

// GCN 2-layer. Radix-partition CSR build; per-node-wave gather aggregation
// with fp16 intermediate storage (halves gather bytes: 128B/row layer1,
// 64B/row layer2); layer-1 agg fused with ReLU + GEMM2 (fp32 accumulate).
// out = Anorm( relu(Anorm(x@W1)+b1) @ W2 ) + b2,  Anorm = D^-1/2 (A+I) D^-1/2.
// h1h = fp16(dinv*(x@W1)); row = relu(dinv*(sum h1h + self)+b1);
// h2h = fp16(dinv*(row@W2)); out = dinv*(sum h2h + self) + b2.

#define THREADS 256
#define PBLK 256      // partition blocks (hist chunking must match)
#define BSHIFT 8      // bucket = dst >> 8 (256 nodes/bucket)

typedef _Float16 h8v __attribute__((ext_vector_type(8)));
typedef _Float16 h4v __attribute__((ext_vector_type(4)));

__device__ __forceinline__ int nt_ld_i(const int* p) {
    return __builtin_nontemporal_load(p);
}

// block-local int64-layout detection (consistent across blocks: same data)
__device__ __forceinline__ int detect64_block(const int* __restrict__ idx, int E,
                                              int* s_flag) {
    if (threadIdx.x == 0) *s_flag = 1;
    __syncthreads();
    int n = (E < 1024) ? E : 1024;
    for (int i = threadIdx.x; i < n; i += THREADS)
        if (idx[2 * i + 1] != 0) *s_flag = 0;  // benign race, only 0 written
    __syncthreads();
    return *s_flag;
}

// ---------------- per-block bucket histogram (+ inline detection) ----------------
__global__ __launch_bounds__(THREADS) void k_hist(const int* __restrict__ idx, int E,
                                                  int* __restrict__ bh, int NB) {
    extern __shared__ int lh[];  // NB + 1
    int is64 = detect64_block(idx, E, &lh[NB]);
    for (int t = threadIdx.x; t < NB; t += THREADS) lh[t] = 0;
    __syncthreads();
    int chunk = (E + PBLK - 1) / PBLK;
    int start = blockIdx.x * chunk;
    int end = min(start + chunk, E);
    for (int e = start + threadIdx.x; e < end; e += THREADS) {
        int d = is64 ? idx[2 * E + 2 * e] : idx[E + e];
        atomicAdd(&lh[d >> BSHIFT], 1);
    }
    __syncthreads();
    for (int t = threadIdx.x; t < NB; t += THREADS)
        bh[blockIdx.x * NB + t] = lh[t];
}

// ---------------- meta: colsum + exclusive scan + per-(block,bucket) bases ----------------
__global__ __launch_bounds__(THREADS) void k_meta(const int* __restrict__ bh,
                                                  int* __restrict__ boff,
                                                  int* __restrict__ bbase, int NB) {
    __shared__ int cnt_s[1024];
    for (int b = threadIdx.x; b < NB; b += THREADS) {
        int s = 0;
        for (int k = 0; k < PBLK; ++k) s += bh[k * NB + b];
        cnt_s[b] = s;
    }
    __syncthreads();
    if (threadIdx.x == 0) {
        int run = 0;
        for (int b = 0; b < NB; ++b) {
            int c = cnt_s[b];
            cnt_s[b] = run;
            boff[b] = run;
            run += c;
        }
        boff[NB] = run;  // == E
    }
    __syncthreads();
    for (int b = threadIdx.x; b < NB; b += THREADS) {
        int run = cnt_s[b];
        for (int k = 0; k < PBLK; ++k) {
            int i = k * NB + b;
            bbase[i] = run;
            run += bh[i];
        }
    }
}

// ---------------- partition: packed (ldst<<24)|src into bucket ranges ----------------
// requires src < 2^24 (N = 100K here)
__global__ __launch_bounds__(THREADS) void k_partition(const int* __restrict__ idx, int E,
                                                       const int* __restrict__ bbase,
                                                       unsigned* __restrict__ pairs, int NB) {
    extern __shared__ int sm[];
    int* lbase = sm;        // NB
    int* lcur  = sm + NB;   // NB (+1 for flag)
    int is64 = detect64_block(idx, E, &lcur[NB]);
    for (int t = threadIdx.x; t < NB; t += THREADS) {
        lbase[t] = bbase[blockIdx.x * NB + t];
        lcur[t] = 0;
    }
    __syncthreads();
    int chunk = (E + PBLK - 1) / PBLK;
    int start = blockIdx.x * chunk;
    int end = min(start + chunk, E);
    for (int e = start + threadIdx.x; e < end; e += THREADS) {
        int s = is64 ? idx[2 * e] : idx[e];
        int d = is64 ? idx[2 * E + 2 * e] : idx[E + e];
        int b = d >> BSHIFT;
        int r = atomicAdd(&lcur[b], 1);
        pairs[lbase[b] + r] = (unsigned)s | ((unsigned)(d & 255) << 24);
    }
}

// ---------------- per-bucket counting sort -> csr_src, row_ptr, dinv ----------------
__global__ __launch_bounds__(THREADS) void k_sort(const unsigned* __restrict__ pairs,
                                                  const int* __restrict__ boff,
                                                  int* __restrict__ csr_src,
                                                  int* __restrict__ row_ptr,
                                                  float* __restrict__ dinv, int N, int NB) {
    __shared__ int cnt[256];
    __shared__ int cur[256];
    __shared__ int wsum[4];
    const int b = blockIdx.x, t = threadIdx.x;
    const int start = boff[b], end = boff[b + 1];
    cnt[t] = 0;
    __syncthreads();
    for (int j = start + t; j < end; j += THREADS)
        atomicAdd(&cnt[pairs[j] >> 24], 1);
    __syncthreads();
    int deg = cnt[t];
    int lane = t & 63, w = t >> 6;
    int v = deg;
#pragma unroll
    for (int o = 1; o < 64; o <<= 1) {
        int u = __shfl_up(v, o);
        if (lane >= o) v += u;
    }
    if (lane == 63) wsum[w] = v;
    __syncthreads();
    int wadd = 0;
#pragma unroll
    for (int k = 0; k < 4; ++k) if (k < w) wadd += wsum[k];
    int pos = start + (v - deg) + wadd;
    cur[t] = pos;
    int node = (b << BSHIFT) + t;
    if (node < N) {
        row_ptr[node] = pos;
        dinv[node] = rsqrtf((float)(deg + 1));  // +1 self loop
    }
    if (b == NB - 1 && t == 0) row_ptr[N] = end;
    __syncthreads();
    for (int j = start + t; j < end; j += THREADS) {
        unsigned p = pairs[j];
        int r = atomicAdd(&cur[p >> 24], 1);
        csr_src[r] = (int)(p & 0xFFFFFFu);
    }
}

// ---------------- GEMM1: h1h = fp16(dinv[row] * (x @ W1))   [N,128]@[128,64] ----------------
__global__ __launch_bounds__(THREADS) void k_gemm1(const float* __restrict__ x,
                                                   const float* __restrict__ W,
                                                   const float* __restrict__ dinv,
                                                   _Float16* __restrict__ h, int N) {
    __shared__ float xs[64][68];
    __shared__ float ws[64][64];
    const int tid = threadIdx.x;
    const int brow = blockIdx.x * 64;
    const int lane = tid & 63, wv = tid >> 6;
    const int jc = (lane & 15) << 2;
    const int rb = (lane >> 4) + (wv << 2);
    float4 acc[4];
    acc[0] = acc[1] = acc[2] = acc[3] = make_float4(0.f, 0.f, 0.f, 0.f);

    for (int kt = 0; kt < 128; kt += 64) {
        for (int f = tid; f < 64 * 16; f += THREADS) {
            int r = f >> 4, k4 = (f & 15) << 2;
            int row = brow + r;
            float4 v = make_float4(0.f, 0.f, 0.f, 0.f);
            if (row < N) v = *(const float4*)&x[(size_t)row * 128 + kt + k4];
            *(float4*)&xs[r][k4] = v;
        }
        for (int f = tid; f < 64 * 16; f += THREADS) {
            int k = f >> 4, c4 = (f & 15) << 2;
            *(float4*)&ws[k][c4] = *(const float4*)&W[(size_t)(kt + k) * 64 + c4];
        }
        __syncthreads();
#pragma unroll
        for (int k = 0; k < 64; k += 4) {
            float4 a[4], b[4];
#pragma unroll
            for (int i = 0; i < 4; ++i) a[i] = *(const float4*)&xs[rb + (i << 4)][k];
#pragma unroll
            for (int kk = 0; kk < 4; ++kk) b[kk] = *(const float4*)&ws[k + kk][jc];
#pragma unroll
            for (int i = 0; i < 4; ++i) {
                const float* ai = (const float*)&a[i];
#pragma unroll
                for (int kk = 0; kk < 4; ++kk) {
                    float av = ai[kk];
                    acc[i].x += av * b[kk].x;
                    acc[i].y += av * b[kk].y;
                    acc[i].z += av * b[kk].z;
                    acc[i].w += av * b[kk].w;
                }
            }
        }
        __syncthreads();
    }
#pragma unroll
    for (int i = 0; i < 4; ++i) {
        int row = brow + rb + (i << 4);
        if (row < N) {
            float dn = dinv[row];
            h4v hv;
            hv.x = (_Float16)(acc[i].x * dn);
            hv.y = (_Float16)(acc[i].y * dn);
            hv.z = (_Float16)(acc[i].z * dn);
            hv.w = (_Float16)(acc[i].w * dn);
            *(h4v*)&h[(size_t)row * 64 + jc] = hv;
        }
    }
}

// ---------------- fused layer-1 agg + bias + ReLU + GEMM2 ----------------
// wave/node: 8 groups x 8 lanes; each group gathers full 128B fp16 rows
// (16B/lane), unroll x2. fp32 accumulate, cross-group shfl reduce.
// row = relu(dinv*(acc+self)+b1) -> LDS rowbuf -> h2h = fp16(dinv*(row@W2)).
__global__ __launch_bounds__(THREADS) void k_agg1f(const int* __restrict__ row_ptr,
                                                   const int* __restrict__ csr,
                                                   const float* __restrict__ dinv,
                                                   const _Float16* __restrict__ hs,
                                                   const float* __restrict__ b1,
                                                   const float* __restrict__ W2,
                                                   _Float16* __restrict__ h2s, int N) {
    __shared__ float w2s[64][32];   // [k][j]; 2-way wave64 aliasing is free
    __shared__ float rowbuf[4][64]; // per-wave relu(o1) row
    const int tid = threadIdx.x;
    for (int f = tid; f < 64 * 8; f += THREADS) {
        int k = f >> 3, c4 = (f & 7) << 2;
        *(float4*)&w2s[k][c4] = *(const float4*)&W2[(size_t)k * 32 + c4];
    }
    __syncthreads();

    const int wid = (blockIdx.x * THREADS + tid) >> 6;
    if (wid >= N) return;
    const int lane = tid & 63;
    const int wv = tid >> 6;
    const int g = lane >> 3, fl = lane & 7;

    const int start = nt_ld_i(&row_ptr[wid]);
    const int end = nt_ld_i(&row_ptr[wid + 1]);
    float acc[8] = {0.f, 0.f, 0.f, 0.f, 0.f, 0.f, 0.f, 0.f};
    int j = start + g;
    for (; j + 8 < end; j += 16) {
        int s0 = nt_ld_i(&csr[j]);
        int s1 = nt_ld_i(&csr[j + 8]);
        h8v v0 = *(const h8v*)&hs[(size_t)s0 * 64 + (fl << 3)];
        h8v v1 = *(const h8v*)&hs[(size_t)s1 * 64 + (fl << 3)];
#pragma unroll
        for (int k = 0; k < 8; ++k) acc[k] += (float)v0[k] + (float)v1[k];
    }
    if (j < end) {
        int s = nt_ld_i(&csr[j]);
        h8v v = *(const h8v*)&hs[(size_t)s * 64 + (fl << 3)];
#pragma unroll
        for (int k = 0; k < 8; ++k) acc[k] += (float)v[k];
    }
#pragma unroll
    for (int off = 8; off < 64; off <<= 1)
#pragma unroll
        for (int k = 0; k < 8; ++k) acc[k] += __shfl_xor(acc[k], off);

    // lane (g,fl) owns feature fl*8+g; pick acc[g] via select tree (no scratch)
    const float dn = dinv[wid];
    {
        float s0 = (g & 1) ? acc[1] : acc[0];
        float s1 = (g & 1) ? acc[3] : acc[2];
        float s2 = (g & 1) ? acc[5] : acc[4];
        float s3 = (g & 1) ? acc[7] : acc[6];
        float t0 = (g & 2) ? s1 : s0;
        float t1 = (g & 2) ? s3 : s2;
        float myv = (g & 4) ? t1 : t0;
        int feat = (fl << 3) + g;
        float selfv = (float)hs[(size_t)wid * 64 + feat];
        float r = fmaxf(dn * (myv + selfv) + b1[feat], 0.f);
        rowbuf[wv][feat] = r;  // 2-way bank aliasing (free); same-wave dep below
    }
    // GEMM2: each lane computes one output col over a 32-wide K half
    const int j2 = lane & 31, kh = (lane >> 5) << 5;
    float a2 = 0.f;
#pragma unroll
    for (int k = 0; k < 32; ++k)
        a2 += rowbuf[wv][kh + k] * w2s[kh + k][j2];
    a2 += __shfl_xor(a2, 32);
    if (lane < 32) h2s[(size_t)wid * 32 + j2] = (_Float16)(dn * a2);
}

// ---------------- layer-2 agg: 16 groups x 4 lanes, full 64B rows, unroll x2 ----------------
__global__ __launch_bounds__(THREADS) void k_agg2(const int* __restrict__ row_ptr,
                                                  const int* __restrict__ csr,
                                                  const float* __restrict__ dinv,
                                                  const _Float16* __restrict__ hs,
                                                  const float* __restrict__ b2,
                                                  float* __restrict__ out, int N) {
    const int wid = (blockIdx.x * blockDim.x + threadIdx.x) >> 6;
    if (wid >= N) return;
    const int lane = threadIdx.x & 63;
    const int g = lane >> 2, fl = lane & 3;
    const int start = nt_ld_i(&row_ptr[wid]);
    const int end = nt_ld_i(&row_ptr[wid + 1]);
    float acc[8] = {0.f, 0.f, 0.f, 0.f, 0.f, 0.f, 0.f, 0.f};
    int j = start + g;
    for (; j + 16 < end; j += 32) {
        int s0 = nt_ld_i(&csr[j]);
        int s1 = nt_ld_i(&csr[j + 16]);
        h8v v0 = *(const h8v*)&hs[(size_t)s0 * 32 + (fl << 3)];
        h8v v1 = *(const h8v*)&hs[(size_t)s1 * 32 + (fl << 3)];
#pragma unroll
        for (int k = 0; k < 8; ++k) acc[k] += (float)v0[k] + (float)v1[k];
    }
    if (j < end) {
        int s = nt_ld_i(&csr[j]);
        h8v v = *(const h8v*)&hs[(size_t)s * 32 + (fl << 3)];
#pragma unroll
        for (int k = 0; k < 8; ++k) acc[k] += (float)v[k];
    }
#pragma unroll
    for (int off = 4; off < 64; off <<= 1)
#pragma unroll
        for (int k = 0; k < 8; ++k) acc[k] += __shfl_xor(acc[k], off);

    if (lane < 4) {
        const float dn = dinv[wid];
        const int fb = fl << 3;
        h8v selfv = *(const h8v*)&hs[(size_t)wid * 32 + fb];
        float4 r0, r1;
        r0.x = dn * (acc[0] + (float)selfv[0]) + b2[fb + 0];
        r0.y = dn * (acc[1] + (float)selfv[1]) + b2[fb + 1];
        r0.z = dn * (acc[2] + (float)selfv[2]) + b2[fb + 2];
        r0.w = dn * (acc[3] + (float)selfv[3]) + b2[fb + 3];
        r1.x = dn * (acc[4] + (float)selfv[4]) + b2[fb + 4];
        r1.y = dn * (acc[5] + (float)selfv[5]) + b2[fb + 5];
        r1.z = dn * (acc[6] + (float)selfv[6]) + b2[fb + 6];
        r1.w = dn * (acc[7] + (float)selfv[7]) + b2[fb + 7];
        *(float4*)&out[(size_t)wid * 32 + fb] = r0;
        *(float4*)&out[(size_t)wid * 32 + fb + 4] = r1;
    }
}

extern "C" void kernel_launch(void* const* d_in, const int* in_sizes, int n_in,
                              void* d_out, int out_size, void* d_ws, size_t ws_size,
                              hipStream_t stream) {
    const int N = in_sizes[0] / 128;
    const int E = in_sizes[1] / 2;
    const float* x  = (const float*)d_in[0];
    const int*   ei = (const int*)d_in[1];
    const float* W1 = (const float*)d_in[2];
    const float* b1 = (const float*)d_in[3];
    const float* W2 = (const float*)d_in[4];
    const float* b2 = (const float*)d_in[5];
    float* out = (float*)d_out;

    const int NB = (N + 255) >> BSHIFT;

    // workspace carve. pairs aliases h1b (dead until k_gemm1, which runs after k_sort;
    // E*4B = 6.4MB <= N*64*2B = 12.8MB).
    float*     dinv    = (float*)d_ws;                    // N
    _Float16*  h1b     = (_Float16*)(dinv + N);           // N*64 fp16
    _Float16*  h2b     = h1b + (size_t)N * 64;            // N*32 fp16
    int*       csr_src = (int*)(h2b + (size_t)N * 32);    // E
    int*       row_ptr = csr_src + E;                     // N+1
    int*       bh      = row_ptr + N + 1;                 // PBLK*NB
    int*       bbase   = bh + (size_t)PBLK * NB;          // PBLK*NB
    int*       boff    = bbase + (size_t)PBLK * NB;       // NB+1
    unsigned*  pairs   = (unsigned*)h1b;                  // E (aliased)

    k_hist<<<PBLK, THREADS, (NB + 1) * 4, stream>>>(ei, E, bh, NB);
    k_meta<<<1, THREADS, 0, stream>>>(bh, boff, bbase, NB);
    k_partition<<<PBLK, THREADS, (2 * NB + 1) * 4, stream>>>(ei, E, bbase, pairs, NB);
    k_sort<<<NB, THREADS, 0, stream>>>(pairs, boff, csr_src, row_ptr, dinv, N, NB);

    k_gemm1<<<(N + 63) / 64, THREADS, 0, stream>>>(x, W1, dinv, h1b, N);
    k_agg1f<<<(N + 3) / 4, THREADS, 0, stream>>>(row_ptr, csr_src, dinv, h1b, b1, W2, h2b, N);
    k_agg2<<<(N + 3) / 4, THREADS, 0, stream>>>(row_ptr, csr_src, dinv, h2b, b2, out, N);
}

// Round 8
// 208.314 us; speedup vs baseline: 3.3656x; 1.1290x over previous
//
#include <hip/hip_runtime.h>
#include <math.h>

// GCN 2-layer. Radix-partition CSR build; per-node-wave gather aggregation
// with fp16 storage AND packed-fp16 (v_pk_add_f16) accumulation; fp32 only
// in the per-node epilogue. Layer-1 agg fused with ReLU + GEMM2 (fp32).
// out = Anorm( relu(Anorm(x@W1)+b1) @ W2 ) + b2,  Anorm = D^-1/2 (A+I) D^-1/2.
// h1h = fp16(dinv*(x@W1)); row = relu(dinv*(sum h1h + self)+b1);
// h2h = fp16(dinv*(row@W2)); out = dinv*(sum h2h + self) + b2.

#define THREADS 256
#define HTHREADS 512  // hist/partition blocks (latency hiding)
#define PBLK 256      // partition blocks (hist chunking must match)
#define BSHIFT 8      // bucket = dst >> 8 (256 nodes/bucket)

typedef _Float16 h8v __attribute__((ext_vector_type(8)));
typedef _Float16 h4v __attribute__((ext_vector_type(4)));
typedef _Float16 h2v __attribute__((ext_vector_type(2)));

union H8U { h8v h; h2v p[4]; int i[4]; };

__device__ __forceinline__ int nt_ld_i(const int* p) {
    return __builtin_nontemporal_load(p);
}

__device__ __forceinline__ h8v shfl_xor_h8(h8v v, int off) {
    H8U u, r;
    u.h = v;
#pragma unroll
    for (int k = 0; k < 4; ++k) r.i[k] = __shfl_xor(u.i[k], off);
    return r.h;
}

// block-local int64-layout detection (consistent across blocks: same data)
__device__ __forceinline__ int detect64_block(const int* __restrict__ idx, int E,
                                              int* s_flag) {
    if (threadIdx.x == 0) *s_flag = 1;
    __syncthreads();
    int n = (E < 1024) ? E : 1024;
    for (int i = threadIdx.x; i < n; i += blockDim.x)
        if (idx[2 * i + 1] != 0) *s_flag = 0;  // benign race, only 0 written
    __syncthreads();
    return *s_flag;
}

// ---------------- per-block bucket histogram (+ inline detection) ----------------
__global__ __launch_bounds__(HTHREADS) void k_hist(const int* __restrict__ idx, int E,
                                                   int* __restrict__ bh, int NB) {
    extern __shared__ int lh[];  // NB + 1
    int is64 = detect64_block(idx, E, &lh[NB]);
    for (int t = threadIdx.x; t < NB; t += HTHREADS) lh[t] = 0;
    __syncthreads();
    int chunk = (E + PBLK - 1) / PBLK;
    int start = blockIdx.x * chunk;
    int end = min(start + chunk, E);
    for (int e = start + threadIdx.x; e < end; e += HTHREADS) {
        int d = is64 ? idx[2 * E + 2 * e] : idx[E + e];
        atomicAdd(&lh[d >> BSHIFT], 1);
    }
    __syncthreads();
    for (int t = threadIdx.x; t < NB; t += HTHREADS)
        bh[blockIdx.x * NB + t] = lh[t];
}

// ---------------- meta: colsum + exclusive scan + per-(block,bucket) bases ----------------
__global__ __launch_bounds__(THREADS) void k_meta(const int* __restrict__ bh,
                                                  int* __restrict__ boff,
                                                  int* __restrict__ bbase, int NB) {
    __shared__ int cnt_s[1024];
    for (int b = threadIdx.x; b < NB; b += THREADS) {
        int s = 0;
        for (int k = 0; k < PBLK; ++k) s += bh[k * NB + b];
        cnt_s[b] = s;
    }
    __syncthreads();
    if (threadIdx.x == 0) {
        int run = 0;
        for (int b = 0; b < NB; ++b) {
            int c = cnt_s[b];
            cnt_s[b] = run;
            boff[b] = run;
            run += c;
        }
        boff[NB] = run;  // == E
    }
    __syncthreads();
    for (int b = threadIdx.x; b < NB; b += THREADS) {
        int run = cnt_s[b];
        for (int k = 0; k < PBLK; ++k) {
            int i = k * NB + b;
            bbase[i] = run;
            run += bh[i];
        }
    }
}

// ---------------- partition: packed (ldst<<24)|src into bucket ranges ----------------
// requires src < 2^24 (N = 100K here)
__global__ __launch_bounds__(HTHREADS) void k_partition(const int* __restrict__ idx, int E,
                                                        const int* __restrict__ bbase,
                                                        unsigned* __restrict__ pairs, int NB) {
    extern __shared__ int sm[];
    int* lbase = sm;        // NB
    int* lcur  = sm + NB;   // NB (+1 for flag)
    int is64 = detect64_block(idx, E, &lcur[NB]);
    for (int t = threadIdx.x; t < NB; t += HTHREADS) {
        lbase[t] = bbase[blockIdx.x * NB + t];
        lcur[t] = 0;
    }
    __syncthreads();
    int chunk = (E + PBLK - 1) / PBLK;
    int start = blockIdx.x * chunk;
    int end = min(start + chunk, E);
    for (int e = start + threadIdx.x; e < end; e += HTHREADS) {
        int s = is64 ? idx[2 * e] : idx[e];
        int d = is64 ? idx[2 * E + 2 * e] : idx[E + e];
        int b = d >> BSHIFT;
        int r = atomicAdd(&lcur[b], 1);
        pairs[lbase[b] + r] = (unsigned)s | ((unsigned)(d & 255) << 24);
    }
}

// ---------------- per-bucket counting sort -> csr_src, row_ptr, dinv ----------------
__global__ __launch_bounds__(THREADS) void k_sort(const unsigned* __restrict__ pairs,
                                                  const int* __restrict__ boff,
                                                  int* __restrict__ csr_src,
                                                  int* __restrict__ row_ptr,
                                                  float* __restrict__ dinv, int N, int NB) {
    __shared__ int cnt[256];
    __shared__ int cur[256];
    __shared__ int wsum[4];
    const int b = blockIdx.x, t = threadIdx.x;
    const int start = boff[b], end = boff[b + 1];
    cnt[t] = 0;
    __syncthreads();
    for (int j = start + t; j < end; j += THREADS)
        atomicAdd(&cnt[pairs[j] >> 24], 1);
    __syncthreads();
    int deg = cnt[t];
    int lane = t & 63, w = t >> 6;
    int v = deg;
#pragma unroll
    for (int o = 1; o < 64; o <<= 1) {
        int u = __shfl_up(v, o);
        if (lane >= o) v += u;
    }
    if (lane == 63) wsum[w] = v;
    __syncthreads();
    int wadd = 0;
#pragma unroll
    for (int k = 0; k < 4; ++k) if (k < w) wadd += wsum[k];
    int pos = start + (v - deg) + wadd;
    cur[t] = pos;
    int node = (b << BSHIFT) + t;
    if (node < N) {
        row_ptr[node] = pos;
        dinv[node] = rsqrtf((float)(deg + 1));  // +1 self loop
    }
    if (b == NB - 1 && t == 0) row_ptr[N] = end;
    __syncthreads();
    for (int j = start + t; j < end; j += THREADS) {
        unsigned p = pairs[j];
        int r = atomicAdd(&cur[p >> 24], 1);
        csr_src[r] = (int)(p & 0xFFFFFFu);
    }
}

// ---------------- GEMM1: h1h = fp16(dinv[row] * (x @ W1))   [N,128]@[128,64] ----------------
__global__ __launch_bounds__(THREADS) void k_gemm1(const float* __restrict__ x,
                                                   const float* __restrict__ W,
                                                   const float* __restrict__ dinv,
                                                   _Float16* __restrict__ h, int N) {
    __shared__ float xs[64][68];
    __shared__ float ws[64][64];
    const int tid = threadIdx.x;
    const int brow = blockIdx.x * 64;
    const int lane = tid & 63, wv = tid >> 6;
    const int jc = (lane & 15) << 2;
    const int rb = (lane >> 4) + (wv << 2);
    float4 acc[4];
    acc[0] = acc[1] = acc[2] = acc[3] = make_float4(0.f, 0.f, 0.f, 0.f);

    for (int kt = 0; kt < 128; kt += 64) {
        for (int f = tid; f < 64 * 16; f += THREADS) {
            int r = f >> 4, k4 = (f & 15) << 2;
            int row = brow + r;
            float4 v = make_float4(0.f, 0.f, 0.f, 0.f);
            if (row < N) v = *(const float4*)&x[(size_t)row * 128 + kt + k4];
            *(float4*)&xs[r][k4] = v;
        }
        for (int f = tid; f < 64 * 16; f += THREADS) {
            int k = f >> 4, c4 = (f & 15) << 2;
            *(float4*)&ws[k][c4] = *(const float4*)&W[(size_t)(kt + k) * 64 + c4];
        }
        __syncthreads();
#pragma unroll
        for (int k = 0; k < 64; k += 4) {
            float4 a[4], b[4];
#pragma unroll
            for (int i = 0; i < 4; ++i) a[i] = *(const float4*)&xs[rb + (i << 4)][k];
#pragma unroll
            for (int kk = 0; kk < 4; ++kk) b[kk] = *(const float4*)&ws[k + kk][jc];
#pragma unroll
            for (int i = 0; i < 4; ++i) {
                const float* ai = (const float*)&a[i];
#pragma unroll
                for (int kk = 0; kk < 4; ++kk) {
                    float av = ai[kk];
                    acc[i].x += av * b[kk].x;
                    acc[i].y += av * b[kk].y;
                    acc[i].z += av * b[kk].z;
                    acc[i].w += av * b[kk].w;
                }
            }
        }
        __syncthreads();
    }
#pragma unroll
    for (int i = 0; i < 4; ++i) {
        int row = brow + rb + (i << 4);
        if (row < N) {
            float dn = dinv[row];
            h4v hv;
            hv.x = (_Float16)(acc[i].x * dn);
            hv.y = (_Float16)(acc[i].y * dn);
            hv.z = (_Float16)(acc[i].z * dn);
            hv.w = (_Float16)(acc[i].w * dn);
            *(h4v*)&h[(size_t)row * 64 + jc] = hv;
        }
    }
}

// ---------------- fused layer-1 agg + bias + ReLU + GEMM2 ----------------
// wave/node: 8 groups x 8 lanes; each group gathers full 128B fp16 rows
// (16B/lane), unroll x2. PACKED fp16 accumulate (v_pk_add_f16) + packed
// shuffle reduce; fp32 only in the per-node epilogue.
__global__ __launch_bounds__(THREADS) void k_agg1f(const int* __restrict__ row_ptr,
                                                   const int* __restrict__ csr,
                                                   const float* __restrict__ dinv,
                                                   const _Float16* __restrict__ hs,
                                                   const float* __restrict__ b1,
                                                   const float* __restrict__ W2,
                                                   _Float16* __restrict__ h2s, int N) {
    __shared__ float w2s[64][32];   // [k][j]; 2-way wave64 aliasing is free
    __shared__ float rowbuf[4][64]; // per-wave relu(o1) row
    const int tid = threadIdx.x;
    for (int f = tid; f < 64 * 8; f += THREADS) {
        int k = f >> 3, c4 = (f & 7) << 2;
        *(float4*)&w2s[k][c4] = *(const float4*)&W2[(size_t)k * 32 + c4];
    }
    __syncthreads();

    const int wid = (blockIdx.x * THREADS + tid) >> 6;
    if (wid >= N) return;
    const int lane = tid & 63;
    const int wv = tid >> 6;
    const int g = lane >> 3, fl = lane & 7;

    const int start = nt_ld_i(&row_ptr[wid]);
    const int end = nt_ld_i(&row_ptr[wid + 1]);
    h8v acc = {0, 0, 0, 0, 0, 0, 0, 0};
    int j = start + g;
    for (; j + 8 < end; j += 16) {
        int s0 = nt_ld_i(&csr[j]);
        int s1 = nt_ld_i(&csr[j + 8]);
        h8v v0 = *(const h8v*)&hs[(size_t)s0 * 64 + (fl << 3)];
        h8v v1 = *(const h8v*)&hs[(size_t)s1 * 64 + (fl << 3)];
        acc += v0;
        acc += v1;
    }
    if (j < end) {
        int s = nt_ld_i(&csr[j]);
        acc += *(const h8v*)&hs[(size_t)s * 64 + (fl << 3)];
    }
    // packed cross-group reduce: after this every lane has the 8 sums of its fl-slice
    acc += shfl_xor_h8(acc, 8);
    acc += shfl_xor_h8(acc, 16);
    acc += shfl_xor_h8(acc, 32);

    // lane (g,fl) owns feature fl*8+g = packed dword g>>1, half g&1 (static select)
    const float dn = dinv[wid];
    {
        H8U u;
        u.h = acc;
        int r01 = (g & 2) ? u.i[1] : u.i[0];
        int r23 = (g & 2) ? u.i[3] : u.i[2];
        int rr = (g & 4) ? r23 : r01;
        h2v pp = __builtin_bit_cast(h2v, rr);
        float myv = (float)((g & 1) ? pp.y : pp.x);
        int feat = (fl << 3) + g;
        float selfv = (float)hs[(size_t)wid * 64 + feat];
        float r = fmaxf(dn * (myv + selfv) + b1[feat], 0.f);
        rowbuf[wv][feat] = r;  // same-wave dep below; no barrier needed
    }
    // GEMM2: each lane computes one output col over a 32-wide K half
    const int j2 = lane & 31, kh = (lane >> 5) << 5;
    float a2 = 0.f;
#pragma unroll
    for (int k = 0; k < 32; ++k)
        a2 += rowbuf[wv][kh + k] * w2s[kh + k][j2];
    a2 += __shfl_xor(a2, 32);
    if (lane < 32) h2s[(size_t)wid * 32 + j2] = (_Float16)(dn * a2);
}

// ---------------- layer-2 agg: 16 groups x 4 lanes, packed fp16 accumulate ----------------
__global__ __launch_bounds__(THREADS) void k_agg2(const int* __restrict__ row_ptr,
                                                  const int* __restrict__ csr,
                                                  const float* __restrict__ dinv,
                                                  const _Float16* __restrict__ hs,
                                                  const float* __restrict__ b2,
                                                  float* __restrict__ out, int N) {
    const int wid = (blockIdx.x * blockDim.x + threadIdx.x) >> 6;
    if (wid >= N) return;
    const int lane = threadIdx.x & 63;
    const int g = lane >> 2, fl = lane & 3;
    const int start = nt_ld_i(&row_ptr[wid]);
    const int end = nt_ld_i(&row_ptr[wid + 1]);
    h8v acc = {0, 0, 0, 0, 0, 0, 0, 0};
    int j = start + g;
    for (; j + 16 < end; j += 32) {
        int s0 = nt_ld_i(&csr[j]);
        int s1 = nt_ld_i(&csr[j + 16]);
        h8v v0 = *(const h8v*)&hs[(size_t)s0 * 32 + (fl << 3)];
        h8v v1 = *(const h8v*)&hs[(size_t)s1 * 32 + (fl << 3)];
        acc += v0;
        acc += v1;
    }
    if (j < end) {
        int s = nt_ld_i(&csr[j]);
        acc += *(const h8v*)&hs[(size_t)s * 32 + (fl << 3)];
    }
    acc += shfl_xor_h8(acc, 4);
    acc += shfl_xor_h8(acc, 8);
    acc += shfl_xor_h8(acc, 16);
    acc += shfl_xor_h8(acc, 32);

    if (lane < 4) {
        const float dn = dinv[wid];
        const int fb = fl << 3;
        h8v selfv = *(const h8v*)&hs[(size_t)wid * 32 + fb];
        float4 r0, r1;
        r0.x = dn * ((float)acc[0] + (float)selfv[0]) + b2[fb + 0];
        r0.y = dn * ((float)acc[1] + (float)selfv[1]) + b2[fb + 1];
        r0.z = dn * ((float)acc[2] + (float)selfv[2]) + b2[fb + 2];
        r0.w = dn * ((float)acc[3] + (float)selfv[3]) + b2[fb + 3];
        r1.x = dn * ((float)acc[4] + (float)selfv[4]) + b2[fb + 4];
        r1.y = dn * ((float)acc[5] + (float)selfv[5]) + b2[fb + 5];
        r1.z = dn * ((float)acc[6] + (float)selfv[6]) + b2[fb + 6];
        r1.w = dn * ((float)acc[7] + (float)selfv[7]) + b2[fb + 7];
        *(float4*)&out[(size_t)wid * 32 + fb] = r0;
        *(float4*)&out[(size_t)wid * 32 + fb + 4] = r1;
    }
}

extern "C" void kernel_launch(void* const* d_in, const int* in_sizes, int n_in,
                              void* d_out, int out_size, void* d_ws, size_t ws_size,
                              hipStream_t stream) {
    const int N = in_sizes[0] / 128;
    const int E = in_sizes[1] / 2;
    const float* x  = (const float*)d_in[0];
    const int*   ei = (const int*)d_in[1];
    const float* W1 = (const float*)d_in[2];
    const float* b1 = (const float*)d_in[3];
    const float* W2 = (const float*)d_in[4];
    const float* b2 = (const float*)d_in[5];
    float* out = (float*)d_out;

    const int NB = (N + 255) >> BSHIFT;

    // workspace carve. pairs aliases h1b (dead until k_gemm1, which runs after k_sort;
    // E*4B = 6.4MB <= N*64*2B = 12.8MB).
    float*     dinv    = (float*)d_ws;                    // N
    _Float16*  h1b     = (_Float16*)(dinv + N);           // N*64 fp16
    _Float16*  h2b     = h1b + (size_t)N * 64;            // N*32 fp16
    int*       csr_src = (int*)(h2b + (size_t)N * 32);    // E
    int*       row_ptr = csr_src + E;                     // N+1
    int*       bh      = row_ptr + N + 1;                 // PBLK*NB
    int*       bbase   = bh + (size_t)PBLK * NB;          // PBLK*NB
    int*       boff    = bbase + (size_t)PBLK * NB;       // NB+1
    unsigned*  pairs   = (unsigned*)h1b;                  // E (aliased)

    k_hist<<<PBLK, HTHREADS, (NB + 1) * 4, stream>>>(ei, E, bh, NB);
    k_meta<<<1, THREADS, 0, stream>>>(bh, boff, bbase, NB);
    k_partition<<<PBLK, HTHREADS, (2 * NB + 1) * 4, stream>>>(ei, E, bbase, pairs, NB);
    k_sort<<<NB, THREADS, 0, stream>>>(pairs, boff, csr_src, row_ptr, dinv, N, NB);

    k_gemm1<<<(N + 63) / 64, THREADS, 0, stream>>>(x, W1, dinv, h1b, N);
    k_agg1f<<<(N + 3) / 4, THREADS, 0, stream>>>(row_ptr, csr_src, dinv, h1b, b1, W2, h2b, N);
    k_agg2<<<(N + 3) / 4, THREADS, 0, stream>>>(row_ptr, csr_src, dinv, h2b, b2, out, N);
}

// Round 9
// 187.501 us; speedup vs baseline: 3.7392x; 1.1110x over previous
//
#include <hip/hip_runtime.h>
#include <math.h>

// GCN 2-layer. Radix-partition CSR build; aggregation with block-staged CSR
// (row_ptr + csr segment in LDS -> only independent row gathers hit global),
// fp16 storage + packed v_pk_add_f16 accumulate; layer-1 agg fused with
// ReLU + GEMM2 (fp32 epilogue).
// out = Anorm( relu(Anorm(x@W1)+b1) @ W2 ) + b2,  Anorm = D^-1/2 (A+I) D^-1/2.

#define THREADS 256
#define HTHREADS 512  // hist/partition blocks
#define PBLK 256      // partition blocks (hist chunking must match)
#define BSHIFT 8      // bucket = dst >> 8 (256 nodes/bucket)
#define AGG_NODES 64  // nodes per aggregation block
#define CSR_LDS 2048  // staged csr entries budget (mean 1024, sigma 32)

typedef _Float16 h8v __attribute__((ext_vector_type(8)));
typedef _Float16 h4v __attribute__((ext_vector_type(4)));
typedef _Float16 h2v __attribute__((ext_vector_type(2)));

union H8U { h8v h; h2v p[4]; int i[4]; };

__device__ __forceinline__ int nt_ld_i(const int* p) {
    return __builtin_nontemporal_load(p);
}

__device__ __forceinline__ h8v shfl_xor_h8(h8v v, int off) {
    H8U u, r;
    u.h = v;
#pragma unroll
    for (int k = 0; k < 4; ++k) r.i[k] = __shfl_xor(u.i[k], off);
    return r.h;
}

// block-local int64-layout detection (consistent across blocks: same data)
__device__ __forceinline__ int detect64_block(const int* __restrict__ idx, int E,
                                              int* s_flag) {
    if (threadIdx.x == 0) *s_flag = 1;
    __syncthreads();
    int n = (E < 1024) ? E : 1024;
    for (int i = threadIdx.x; i < n; i += blockDim.x)
        if (idx[2 * i + 1] != 0) *s_flag = 0;  // benign race, only 0 written
    __syncthreads();
    return *s_flag;
}

// ---------------- per-block bucket histogram (+ inline detection) ----------------
__global__ __launch_bounds__(HTHREADS) void k_hist(const int* __restrict__ idx, int E,
                                                   int* __restrict__ bh, int NB) {
    extern __shared__ int lh[];  // NB + 1
    int is64 = detect64_block(idx, E, &lh[NB]);
    for (int t = threadIdx.x; t < NB; t += HTHREADS) lh[t] = 0;
    __syncthreads();
    int chunk = (E + PBLK - 1) / PBLK;
    int start = blockIdx.x * chunk;
    int end = min(start + chunk, E);
    for (int e = start + threadIdx.x; e < end; e += HTHREADS) {
        int d = is64 ? idx[2 * E + 2 * e] : idx[E + e];
        atomicAdd(&lh[d >> BSHIFT], 1);
    }
    __syncthreads();
    for (int t = threadIdx.x; t < NB; t += HTHREADS)
        bh[blockIdx.x * NB + t] = lh[t];
}

// ---------------- meta: colsum + exclusive scan + per-(block,bucket) bases ----------------
__global__ __launch_bounds__(THREADS) void k_meta(const int* __restrict__ bh,
                                                  int* __restrict__ boff,
                                                  int* __restrict__ bbase, int NB) {
    __shared__ int cnt_s[1024];
    for (int b = threadIdx.x; b < NB; b += THREADS) {
        int s = 0;
        for (int k = 0; k < PBLK; ++k) s += bh[k * NB + b];
        cnt_s[b] = s;
    }
    __syncthreads();
    if (threadIdx.x == 0) {
        int run = 0;
        for (int b = 0; b < NB; ++b) {
            int c = cnt_s[b];
            cnt_s[b] = run;
            boff[b] = run;
            run += c;
        }
        boff[NB] = run;  // == E
    }
    __syncthreads();
    for (int b = threadIdx.x; b < NB; b += THREADS) {
        int run = cnt_s[b];
        for (int k = 0; k < PBLK; ++k) {
            int i = k * NB + b;
            bbase[i] = run;
            run += bh[i];
        }
    }
}

// ---------------- partition: packed (ldst<<24)|src into bucket ranges ----------------
// requires src < 2^24 (N = 100K here)
__global__ __launch_bounds__(HTHREADS) void k_partition(const int* __restrict__ idx, int E,
                                                        const int* __restrict__ bbase,
                                                        unsigned* __restrict__ pairs, int NB) {
    extern __shared__ int sm[];
    int* lbase = sm;        // NB
    int* lcur  = sm + NB;   // NB (+1 for flag)
    int is64 = detect64_block(idx, E, &lcur[NB]);
    for (int t = threadIdx.x; t < NB; t += HTHREADS) {
        lbase[t] = bbase[blockIdx.x * NB + t];
        lcur[t] = 0;
    }
    __syncthreads();
    int chunk = (E + PBLK - 1) / PBLK;
    int start = blockIdx.x * chunk;
    int end = min(start + chunk, E);
    for (int e = start + threadIdx.x; e < end; e += HTHREADS) {
        int s = is64 ? idx[2 * e] : idx[e];
        int d = is64 ? idx[2 * E + 2 * e] : idx[E + e];
        int b = d >> BSHIFT;
        int r = atomicAdd(&lcur[b], 1);
        pairs[lbase[b] + r] = (unsigned)s | ((unsigned)(d & 255) << 24);
    }
}

// ---------------- per-bucket counting sort -> csr_src, row_ptr, dinv ----------------
__global__ __launch_bounds__(THREADS) void k_sort(const unsigned* __restrict__ pairs,
                                                  const int* __restrict__ boff,
                                                  int* __restrict__ csr_src,
                                                  int* __restrict__ row_ptr,
                                                  float* __restrict__ dinv, int N, int NB) {
    __shared__ int cnt[256];
    __shared__ int cur[256];
    __shared__ int wsum[4];
    const int b = blockIdx.x, t = threadIdx.x;
    const int start = boff[b], end = boff[b + 1];
    cnt[t] = 0;
    __syncthreads();
    for (int j = start + t; j < end; j += THREADS)
        atomicAdd(&cnt[pairs[j] >> 24], 1);
    __syncthreads();
    int deg = cnt[t];
    int lane = t & 63, w = t >> 6;
    int v = deg;
#pragma unroll
    for (int o = 1; o < 64; o <<= 1) {
        int u = __shfl_up(v, o);
        if (lane >= o) v += u;
    }
    if (lane == 63) wsum[w] = v;
    __syncthreads();
    int wadd = 0;
#pragma unroll
    for (int k = 0; k < 4; ++k) if (k < w) wadd += wsum[k];
    int pos = start + (v - deg) + wadd;
    cur[t] = pos;
    int node = (b << BSHIFT) + t;
    if (node < N) {
        row_ptr[node] = pos;
        dinv[node] = rsqrtf((float)(deg + 1));  // +1 self loop
    }
    if (b == NB - 1 && t == 0) row_ptr[N] = end;
    __syncthreads();
    for (int j = start + t; j < end; j += THREADS) {
        unsigned p = pairs[j];
        int r = atomicAdd(&cur[p >> 24], 1);
        csr_src[r] = (int)(p & 0xFFFFFFu);
    }
}

// ---------------- GEMM1: h1h = fp16(dinv[row] * (x @ W1))   [N,128]@[128,64] ----------------
__global__ __launch_bounds__(THREADS) void k_gemm1(const float* __restrict__ x,
                                                   const float* __restrict__ W,
                                                   const float* __restrict__ dinv,
                                                   _Float16* __restrict__ h, int N) {
    __shared__ float xs[64][68];
    __shared__ float ws[64][64];
    const int tid = threadIdx.x;
    const int brow = blockIdx.x * 64;
    const int lane = tid & 63, wv = tid >> 6;
    const int jc = (lane & 15) << 2;
    const int rb = (lane >> 4) + (wv << 2);
    float4 acc[4];
    acc[0] = acc[1] = acc[2] = acc[3] = make_float4(0.f, 0.f, 0.f, 0.f);

    for (int kt = 0; kt < 128; kt += 64) {
        for (int f = tid; f < 64 * 16; f += THREADS) {
            int r = f >> 4, k4 = (f & 15) << 2;
            int row = brow + r;
            float4 v = make_float4(0.f, 0.f, 0.f, 0.f);
            if (row < N) v = *(const float4*)&x[(size_t)row * 128 + kt + k4];
            *(float4*)&xs[r][k4] = v;
        }
        for (int f = tid; f < 64 * 16; f += THREADS) {
            int k = f >> 4, c4 = (f & 15) << 2;
            *(float4*)&ws[k][c4] = *(const float4*)&W[(size_t)(kt + k) * 64 + c4];
        }
        __syncthreads();
#pragma unroll
        for (int k = 0; k < 64; k += 4) {
            float4 a[4], b[4];
#pragma unroll
            for (int i = 0; i < 4; ++i) a[i] = *(const float4*)&xs[rb + (i << 4)][k];
#pragma unroll
            for (int kk = 0; kk < 4; ++kk) b[kk] = *(const float4*)&ws[k + kk][jc];
#pragma unroll
            for (int i = 0; i < 4; ++i) {
                const float* ai = (const float*)&a[i];
#pragma unroll
                for (int kk = 0; kk < 4; ++kk) {
                    float av = ai[kk];
                    acc[i].x += av * b[kk].x;
                    acc[i].y += av * b[kk].y;
                    acc[i].z += av * b[kk].z;
                    acc[i].w += av * b[kk].w;
                }
            }
        }
        __syncthreads();
    }
#pragma unroll
    for (int i = 0; i < 4; ++i) {
        int row = brow + rb + (i << 4);
        if (row < N) {
            float dn = dinv[row];
            h4v hv;
            hv.x = (_Float16)(acc[i].x * dn);
            hv.y = (_Float16)(acc[i].y * dn);
            hv.z = (_Float16)(acc[i].z * dn);
            hv.w = (_Float16)(acc[i].w * dn);
            *(h4v*)&h[(size_t)row * 64 + jc] = hv;
        }
    }
}

// ---------------- fused layer-1 agg + bias + ReLU + GEMM2 (block-staged CSR) ----------------
// block = 64 nodes: stage row_ptr[65] + csr segment (<=2048, fallback global).
// wave = 16 nodes, per node 8 groups x 8 lanes gather 128B fp16 rows, packed
// fp16 accumulate, shuffle reduce; relu row -> LDS rowbuf -> GEMM2 -> h2s fp16.
__global__ __launch_bounds__(THREADS) void k_agg1f(const int* __restrict__ row_ptr,
                                                   const int* __restrict__ csr,
                                                   const float* __restrict__ dinv,
                                                   const _Float16* __restrict__ hs,
                                                   const float* __restrict__ b1,
                                                   const float* __restrict__ W2,
                                                   _Float16* __restrict__ h2s, int N) {
    __shared__ float w2s[64][32];        // 8KB
    __shared__ float rowbuf[4][64];      // 1KB
    __shared__ int rp_s[AGG_NODES + 1];
    __shared__ int csr_s[CSR_LDS];       // 8KB
    const int tid = threadIdx.x;
    for (int f = tid; f < 64 * 8; f += THREADS) {
        int k = f >> 3, c4 = (f & 7) << 2;
        *(float4*)&w2s[k][c4] = *(const float4*)&W2[(size_t)k * 32 + c4];
    }
    const int nbase = blockIdx.x * AGG_NODES;
    const int nend = min(nbase + AGG_NODES, N);
    const int ncnt = nend - nbase;
    if (tid <= ncnt) rp_s[tid] = row_ptr[nbase + tid];
    __syncthreads();
    const int seg0 = rp_s[0];
    const int seglen = rp_s[ncnt] - seg0;
    const bool inlds = (seglen <= CSR_LDS);
    if (inlds)
        for (int t = tid; t < seglen; t += THREADS) csr_s[t] = nt_ld_i(&csr[seg0 + t]);
    __syncthreads();

    const int wv = tid >> 6, lane = tid & 63;
    const int g = lane >> 3, fl = lane & 7;
    const int j2 = lane & 31, kh = (lane >> 5) << 5;

    for (int i = 0; i < 16; ++i) {
        const int nloc = (wv << 4) + i;
        const int node = nbase + nloc;
        if (node >= nend) break;
        const int start = rp_s[nloc], end = rp_s[nloc + 1];
        h8v acc = {0, 0, 0, 0, 0, 0, 0, 0};
        if (inlds) {
            int j = start - seg0 + g;
            const int e_ = end - seg0;
            for (; j + 8 < e_; j += 16) {
                int s0 = csr_s[j];
                int s1 = csr_s[j + 8];
                h8v v0 = *(const h8v*)&hs[(size_t)s0 * 64 + (fl << 3)];
                h8v v1 = *(const h8v*)&hs[(size_t)s1 * 64 + (fl << 3)];
                acc += v0;
                acc += v1;
            }
            if (j < e_) {
                int s = csr_s[j];
                acc += *(const h8v*)&hs[(size_t)s * 64 + (fl << 3)];
            }
        } else {
            int j = start + g;
            for (; j + 8 < end; j += 16) {
                int s0 = nt_ld_i(&csr[j]);
                int s1 = nt_ld_i(&csr[j + 8]);
                h8v v0 = *(const h8v*)&hs[(size_t)s0 * 64 + (fl << 3)];
                h8v v1 = *(const h8v*)&hs[(size_t)s1 * 64 + (fl << 3)];
                acc += v0;
                acc += v1;
            }
            if (j < end) {
                int s = nt_ld_i(&csr[j]);
                acc += *(const h8v*)&hs[(size_t)s * 64 + (fl << 3)];
            }
        }
        acc += shfl_xor_h8(acc, 8);
        acc += shfl_xor_h8(acc, 16);
        acc += shfl_xor_h8(acc, 32);

        const float dn = dinv[node];
        {
            H8U u;
            u.h = acc;
            int r01 = (g & 2) ? u.i[1] : u.i[0];
            int r23 = (g & 2) ? u.i[3] : u.i[2];
            int rr = (g & 4) ? r23 : r01;
            h2v pp = __builtin_bit_cast(h2v, rr);
            float myv = (float)((g & 1) ? pp.y : pp.x);
            int feat = (fl << 3) + g;
            float selfv = (float)hs[(size_t)node * 64 + feat];
            float r = fmaxf(dn * (myv + selfv) + b1[feat], 0.f);
            rowbuf[wv][feat] = r;  // same-wave dep below; no barrier needed
        }
        float a2 = 0.f;
#pragma unroll
        for (int k = 0; k < 32; ++k)
            a2 += rowbuf[wv][kh + k] * w2s[kh + k][j2];
        a2 += __shfl_xor(a2, 32);
        if (lane < 32) h2s[(size_t)node * 32 + j2] = (_Float16)(dn * a2);
    }
}

// ---------------- layer-2 agg (block-staged CSR): 16 groups x 4 lanes ----------------
__global__ __launch_bounds__(THREADS) void k_agg2(const int* __restrict__ row_ptr,
                                                  const int* __restrict__ csr,
                                                  const float* __restrict__ dinv,
                                                  const _Float16* __restrict__ hs,
                                                  const float* __restrict__ b2,
                                                  float* __restrict__ out, int N) {
    __shared__ int rp_s[AGG_NODES + 1];
    __shared__ int csr_s[CSR_LDS];
    const int tid = threadIdx.x;
    const int nbase = blockIdx.x * AGG_NODES;
    const int nend = min(nbase + AGG_NODES, N);
    const int ncnt = nend - nbase;
    if (tid <= ncnt) rp_s[tid] = row_ptr[nbase + tid];
    __syncthreads();
    const int seg0 = rp_s[0];
    const int seglen = rp_s[ncnt] - seg0;
    const bool inlds = (seglen <= CSR_LDS);
    if (inlds)
        for (int t = tid; t < seglen; t += THREADS) csr_s[t] = nt_ld_i(&csr[seg0 + t]);
    __syncthreads();

    const int wv = tid >> 6, lane = tid & 63;
    const int g = lane >> 2, fl = lane & 3;

    for (int i = 0; i < 16; ++i) {
        const int nloc = (wv << 4) + i;
        const int node = nbase + nloc;
        if (node >= nend) break;
        const int start = rp_s[nloc], end = rp_s[nloc + 1];
        h8v acc = {0, 0, 0, 0, 0, 0, 0, 0};
        if (inlds) {
            int j = start - seg0 + g;
            const int e_ = end - seg0;
            for (; j + 16 < e_; j += 32) {
                int s0 = csr_s[j];
                int s1 = csr_s[j + 16];
                h8v v0 = *(const h8v*)&hs[(size_t)s0 * 32 + (fl << 3)];
                h8v v1 = *(const h8v*)&hs[(size_t)s1 * 32 + (fl << 3)];
                acc += v0;
                acc += v1;
            }
            if (j < e_) {
                int s = csr_s[j];
                acc += *(const h8v*)&hs[(size_t)s * 32 + (fl << 3)];
            }
        } else {
            int j = start + g;
            for (; j + 16 < end; j += 32) {
                int s0 = nt_ld_i(&csr[j]);
                int s1 = nt_ld_i(&csr[j + 16]);
                h8v v0 = *(const h8v*)&hs[(size_t)s0 * 32 + (fl << 3)];
                h8v v1 = *(const h8v*)&hs[(size_t)s1 * 32 + (fl << 3)];
                acc += v0;
                acc += v1;
            }
            if (j < end) {
                int s = nt_ld_i(&csr[j]);
                acc += *(const h8v*)&hs[(size_t)s * 32 + (fl << 3)];
            }
        }
        acc += shfl_xor_h8(acc, 4);
        acc += shfl_xor_h8(acc, 8);
        acc += shfl_xor_h8(acc, 16);
        acc += shfl_xor_h8(acc, 32);

        if (lane < 4) {
            const float dn = dinv[node];
            const int fb = fl << 3;
            h8v selfv = *(const h8v*)&hs[(size_t)node * 32 + fb];
            float4 r0, r1;
            r0.x = dn * ((float)acc[0] + (float)selfv[0]) + b2[fb + 0];
            r0.y = dn * ((float)acc[1] + (float)selfv[1]) + b2[fb + 1];
            r0.z = dn * ((float)acc[2] + (float)selfv[2]) + b2[fb + 2];
            r0.w = dn * ((float)acc[3] + (float)selfv[3]) + b2[fb + 3];
            r1.x = dn * ((float)acc[4] + (float)selfv[4]) + b2[fb + 4];
            r1.y = dn * ((float)acc[5] + (float)selfv[5]) + b2[fb + 5];
            r1.z = dn * ((float)acc[6] + (float)selfv[6]) + b2[fb + 6];
            r1.w = dn * ((float)acc[7] + (float)selfv[7]) + b2[fb + 7];
            *(float4*)&out[(size_t)node * 32 + fb] = r0;
            *(float4*)&out[(size_t)node * 32 + fb + 4] = r1;
        }
    }
}

extern "C" void kernel_launch(void* const* d_in, const int* in_sizes, int n_in,
                              void* d_out, int out_size, void* d_ws, size_t ws_size,
                              hipStream_t stream) {
    const int N = in_sizes[0] / 128;
    const int E = in_sizes[1] / 2;
    const float* x  = (const float*)d_in[0];
    const int*   ei = (const int*)d_in[1];
    const float* W1 = (const float*)d_in[2];
    const float* b1 = (const float*)d_in[3];
    const float* W2 = (const float*)d_in[4];
    const float* b2 = (const float*)d_in[5];
    float* out = (float*)d_out;

    const int NB = (N + 255) >> BSHIFT;

    // workspace carve. pairs aliases h1b (dead until k_gemm1, which runs after k_sort;
    // E*4B = 6.4MB <= N*64*2B = 12.8MB).
    float*     dinv    = (float*)d_ws;                    // N
    _Float16*  h1b     = (_Float16*)(dinv + N);           // N*64 fp16
    _Float16*  h2b     = h1b + (size_t)N * 64;            // N*32 fp16
    int*       csr_src = (int*)(h2b + (size_t)N * 32);    // E
    int*       row_ptr = csr_src + E;                     // N+1
    int*       bh      = row_ptr + N + 1;                 // PBLK*NB
    int*       bbase   = bh + (size_t)PBLK * NB;          // PBLK*NB
    int*       boff    = bbase + (size_t)PBLK * NB;       // NB+1
    unsigned*  pairs   = (unsigned*)h1b;                  // E (aliased)

    k_hist<<<PBLK, HTHREADS, (NB + 1) * 4, stream>>>(ei, E, bh, NB);
    k_meta<<<1, THREADS, 0, stream>>>(bh, boff, bbase, NB);
    k_partition<<<PBLK, HTHREADS, (2 * NB + 1) * 4, stream>>>(ei, E, bbase, pairs, NB);
    k_sort<<<NB, THREADS, 0, stream>>>(pairs, boff, csr_src, row_ptr, dinv, N, NB);

    k_gemm1<<<(N + 63) / 64, THREADS, 0, stream>>>(x, W1, dinv, h1b, N);
    const int ablk = (N + AGG_NODES - 1) / AGG_NODES;
    k_agg1f<<<ablk, THREADS, 0, stream>>>(row_ptr, csr_src, dinv, h1b, b1, W2, h2b, N);
    k_agg2<<<ablk, THREADS, 0, stream>>>(row_ptr, csr_src, dinv, h2b, b2, out, N);
}

// Round 10
// 141.046 us; speedup vs baseline: 4.9707x; 1.3294x over previous
//
#include <hip/hip_runtime.h>
#include <math.h>

// GCN 2-layer. Radix-partition CSR build; aggregation with block-staged CSR
// and GROUP-PER-NODE gathers: each 8-lane (layer1) / 4-lane (layer2) group
// owns one node and covers the full fp16 row -> 8/16 rows in flight per wave
// instruction, no cross-lane reduce. fp16 storage, dual packed-fp16 accum
// combined in fp32. Layer-1 agg fused with ReLU + GEMM2.
// out = Anorm( relu(Anorm(x@W1)+b1) @ W2 ) + b2,  Anorm = D^-1/2 (A+I) D^-1/2.

#define THREADS 256
#define HTHREADS 512  // hist/partition blocks
#define PBLK 256      // partition blocks (hist chunking; k_colsum assumes ==THREADS)
#define BSHIFT 8      // bucket = dst >> 8 (256 nodes/bucket)
#define AGG_NODES 64  // nodes per aggregation block
#define CSR_LDS 2048  // staged csr entries budget (mean 1024)

typedef _Float16 h8v __attribute__((ext_vector_type(8)));
typedef _Float16 h4v __attribute__((ext_vector_type(4)));

__device__ __forceinline__ int nt_ld_i(const int* p) {
    return __builtin_nontemporal_load(p);
}

// block-local int64-layout detection (consistent across blocks: same data)
__device__ __forceinline__ int detect64_block(const int* __restrict__ idx, int E,
                                              int* s_flag) {
    if (threadIdx.x == 0) *s_flag = 1;
    __syncthreads();
    int n = (E < 1024) ? E : 1024;
    for (int i = threadIdx.x; i < n; i += blockDim.x)
        if (idx[2 * i + 1] != 0) *s_flag = 0;  // benign race, only 0 written
    __syncthreads();
    return *s_flag;
}

// ---------------- per-block bucket histogram (+ inline detection) ----------------
__global__ __launch_bounds__(HTHREADS) void k_hist(const int* __restrict__ idx, int E,
                                                   int* __restrict__ bh, int NB) {
    extern __shared__ int lh[];  // NB + 1
    int is64 = detect64_block(idx, E, &lh[NB]);
    for (int t = threadIdx.x; t < NB; t += HTHREADS) lh[t] = 0;
    __syncthreads();
    int chunk = (E + PBLK - 1) / PBLK;
    int start = blockIdx.x * chunk;
    int end = min(start + chunk, E);
    for (int e = start + threadIdx.x; e < end; e += HTHREADS) {
        int d = is64 ? idx[2 * E + 2 * e] : idx[E + e];
        atomicAdd(&lh[d >> BSHIFT], 1);
    }
    __syncthreads();
    for (int t = threadIdx.x; t < NB; t += HTHREADS)
        bh[blockIdx.x * NB + t] = lh[t];
}

// ---------------- bucket totals: one block per bucket ----------------
__global__ __launch_bounds__(THREADS) void k_colsum(const int* __restrict__ bh,
                                                    int* __restrict__ bcnt, int NB) {
    __shared__ int ws[4];
    int b = blockIdx.x;
    int v = bh[threadIdx.x * NB + b];  // PBLK == THREADS
    int lane = threadIdx.x & 63, w = threadIdx.x >> 6;
#pragma unroll
    for (int o = 32; o; o >>= 1) v += __shfl_down(v, o);
    if (lane == 0) ws[w] = v;
    __syncthreads();
    if (threadIdx.x == 0) bcnt[b] = ws[0] + ws[1] + ws[2] + ws[3];
}

// ---------------- exclusive scan of bucket totals (1 block) ----------------
__global__ __launch_bounds__(THREADS) void k_scan(const int* __restrict__ cnt,
                                                  int* __restrict__ off, int NB) {
    __shared__ int wsum[4];
    __shared__ int carry_s;
    if (threadIdx.x == 0) carry_s = 0;
    __syncthreads();
    int t = threadIdx.x, lane = t & 63, w = t >> 6;
    for (int base = 0; base < NB; base += THREADS) {
        int i = base + t;
        int raw = (i < NB) ? cnt[i] : 0;
        int v = raw;
#pragma unroll
        for (int o = 1; o < 64; o <<= 1) {
            int u = __shfl_up(v, o);
            if (lane >= o) v += u;
        }
        if (lane == 63) wsum[w] = v;
        __syncthreads();
        int c0 = carry_s;
        int wadd = 0;
#pragma unroll
        for (int k = 0; k < 4; ++k) if (k < w) wadd += wsum[k];
        if (i < NB) off[i] = v - raw + wadd + c0;
        __syncthreads();
        if (t == 0) carry_s += wsum[0] + wsum[1] + wsum[2] + wsum[3];
        __syncthreads();
    }
    if (t == 0) off[NB] = carry_s;  // == E
}

// ---------------- per-(block,bucket) bases: one wave per bucket ----------------
__global__ __launch_bounds__(64) void k_bbase(const int* __restrict__ bh,
                                              const int* __restrict__ boff,
                                              int* __restrict__ bbase, int NB) {
    int b = blockIdx.x;
    int lane = threadIdx.x;
    int carry = boff[b];
    for (int base = 0; base < PBLK; base += 64) {
        int idx = (base + lane) * NB + b;
        int raw = bh[idx];
        int v = raw;
#pragma unroll
        for (int o = 1; o < 64; o <<= 1) {
            int u = __shfl_up(v, o);
            if (lane >= o) v += u;
        }
        bbase[idx] = carry + v - raw;
        carry += __shfl(v, 63);
    }
}

// ---------------- partition: packed (ldst<<24)|src into bucket ranges ----------------
// requires src < 2^24 (N = 100K here)
__global__ __launch_bounds__(HTHREADS) void k_partition(const int* __restrict__ idx, int E,
                                                        const int* __restrict__ bbase,
                                                        unsigned* __restrict__ pairs, int NB) {
    extern __shared__ int sm[];
    int* lbase = sm;        // NB
    int* lcur  = sm + NB;   // NB (+1 for flag)
    int is64 = detect64_block(idx, E, &lcur[NB]);
    for (int t = threadIdx.x; t < NB; t += HTHREADS) {
        lbase[t] = bbase[blockIdx.x * NB + t];
        lcur[t] = 0;
    }
    __syncthreads();
    int chunk = (E + PBLK - 1) / PBLK;
    int start = blockIdx.x * chunk;
    int end = min(start + chunk, E);
    for (int e = start + threadIdx.x; e < end; e += HTHREADS) {
        int s = is64 ? idx[2 * e] : idx[e];
        int d = is64 ? idx[2 * E + 2 * e] : idx[E + e];
        int b = d >> BSHIFT;
        int r = atomicAdd(&lcur[b], 1);
        pairs[lbase[b] + r] = (unsigned)s | ((unsigned)(d & 255) << 24);
    }
}

// ---------------- per-bucket counting sort -> csr_src, row_ptr, dinv ----------------
__global__ __launch_bounds__(THREADS) void k_sort(const unsigned* __restrict__ pairs,
                                                  const int* __restrict__ boff,
                                                  int* __restrict__ csr_src,
                                                  int* __restrict__ row_ptr,
                                                  float* __restrict__ dinv, int N, int NB) {
    __shared__ int cnt[256];
    __shared__ int cur[256];
    __shared__ int wsum[4];
    const int b = blockIdx.x, t = threadIdx.x;
    const int start = boff[b], end = boff[b + 1];
    cnt[t] = 0;
    __syncthreads();
    for (int j = start + t; j < end; j += THREADS)
        atomicAdd(&cnt[pairs[j] >> 24], 1);
    __syncthreads();
    int deg = cnt[t];
    int lane = t & 63, w = t >> 6;
    int v = deg;
#pragma unroll
    for (int o = 1; o < 64; o <<= 1) {
        int u = __shfl_up(v, o);
        if (lane >= o) v += u;
    }
    if (lane == 63) wsum[w] = v;
    __syncthreads();
    int wadd = 0;
#pragma unroll
    for (int k = 0; k < 4; ++k) if (k < w) wadd += wsum[k];
    int pos = start + (v - deg) + wadd;
    cur[t] = pos;
    int node = (b << BSHIFT) + t;
    if (node < N) {
        row_ptr[node] = pos;
        dinv[node] = rsqrtf((float)(deg + 1));  // +1 self loop
    }
    if (b == NB - 1 && t == 0) row_ptr[N] = end;
    __syncthreads();
    for (int j = start + t; j < end; j += THREADS) {
        unsigned p = pairs[j];
        int r = atomicAdd(&cur[p >> 24], 1);
        csr_src[r] = (int)(p & 0xFFFFFFu);
    }
}

// ---------------- GEMM1: h1h = fp16(dinv[row] * (x @ W1))   [N,128]@[128,64] ----------------
__global__ __launch_bounds__(THREADS) void k_gemm1(const float* __restrict__ x,
                                                   const float* __restrict__ W,
                                                   const float* __restrict__ dinv,
                                                   _Float16* __restrict__ h, int N) {
    __shared__ float xs[64][68];
    __shared__ float ws[64][64];
    const int tid = threadIdx.x;
    const int brow = blockIdx.x * 64;
    const int lane = tid & 63, wv = tid >> 6;
    const int jc = (lane & 15) << 2;
    const int rb = (lane >> 4) + (wv << 2);
    float4 acc[4];
    acc[0] = acc[1] = acc[2] = acc[3] = make_float4(0.f, 0.f, 0.f, 0.f);

    for (int kt = 0; kt < 128; kt += 64) {
        for (int f = tid; f < 64 * 16; f += THREADS) {
            int r = f >> 4, k4 = (f & 15) << 2;
            int row = brow + r;
            float4 v = make_float4(0.f, 0.f, 0.f, 0.f);
            if (row < N) v = *(const float4*)&x[(size_t)row * 128 + kt + k4];
            *(float4*)&xs[r][k4] = v;
        }
        for (int f = tid; f < 64 * 16; f += THREADS) {
            int k = f >> 4, c4 = (f & 15) << 2;
            *(float4*)&ws[k][c4] = *(const float4*)&W[(size_t)(kt + k) * 64 + c4];
        }
        __syncthreads();
#pragma unroll
        for (int k = 0; k < 64; k += 4) {
            float4 a[4], b[4];
#pragma unroll
            for (int i = 0; i < 4; ++i) a[i] = *(const float4*)&xs[rb + (i << 4)][k];
#pragma unroll
            for (int kk = 0; kk < 4; ++kk) b[kk] = *(const float4*)&ws[k + kk][jc];
#pragma unroll
            for (int i = 0; i < 4; ++i) {
                const float* ai = (const float*)&a[i];
#pragma unroll
                for (int kk = 0; kk < 4; ++kk) {
                    float av = ai[kk];
                    acc[i].x += av * b[kk].x;
                    acc[i].y += av * b[kk].y;
                    acc[i].z += av * b[kk].z;
                    acc[i].w += av * b[kk].w;
                }
            }
        }
        __syncthreads();
    }
#pragma unroll
    for (int i = 0; i < 4; ++i) {
        int row = brow + rb + (i << 4);
        if (row < N) {
            float dn = dinv[row];
            h4v hv;
            hv.x = (_Float16)(acc[i].x * dn);
            hv.y = (_Float16)(acc[i].y * dn);
            hv.z = (_Float16)(acc[i].z * dn);
            hv.w = (_Float16)(acc[i].w * dn);
            *(h4v*)&h[(size_t)row * 64 + jc] = hv;
        }
    }
}

// ---------------- fused layer-1 agg + bias + ReLU + GEMM2 (group-per-node) ----------------
// block = 64 nodes (staged row_ptr/dinv/csr). Each 8-lane group owns one node;
// its 8 lanes cover the 128B fp16 row -> per wave load-step 8 rows in flight.
// No cross-lane reduce. Dual fp16 accumulators -> fp32 combine. Then per-node
// row -> rowbuf (padded) -> GEMM2: 4 cols/lane, full-K dots.
__global__ __launch_bounds__(THREADS) void k_agg1f(const int* __restrict__ row_ptr,
                                                   const int* __restrict__ csr,
                                                   const float* __restrict__ dinv,
                                                   const _Float16* __restrict__ hs,
                                                   const float* __restrict__ b1,
                                                   const float* __restrict__ W2,
                                                   _Float16* __restrict__ h2s, int N) {
    __shared__ float w2s[64][32];          // 8KB
    __shared__ float rowbuf[4][8][68];     // 8.5KB, padded (+4) for bank spread
    __shared__ int rp_s[AGG_NODES + 1];
    __shared__ float dinv_s[AGG_NODES];
    __shared__ int csr_s[CSR_LDS];         // 8KB
    const int tid = threadIdx.x;
    for (int f = tid; f < 64 * 8; f += THREADS) {
        int k = f >> 3, c4 = (f & 7) << 2;
        *(float4*)&w2s[k][c4] = *(const float4*)&W2[(size_t)k * 32 + c4];
    }
    const int nbase = blockIdx.x * AGG_NODES;
    const int nend = min(nbase + AGG_NODES, N);
    const int ncnt = nend - nbase;
    if (tid <= ncnt) rp_s[tid] = row_ptr[nbase + tid];
    if (tid < ncnt) dinv_s[tid] = dinv[nbase + tid];
    __syncthreads();
    const int seg0 = rp_s[0];
    const int seglen = rp_s[ncnt] - seg0;
    const bool inlds = (seglen <= CSR_LDS);
    if (inlds)
        for (int t = tid; t < seglen; t += THREADS) csr_s[t] = nt_ld_i(&csr[seg0 + t]);
    __syncthreads();

    const int wv = tid >> 6, lane = tid & 63;
    const int g = lane >> 3, fl = lane & 7;
    const int fb = fl << 3;

    for (int c = 0; c < 2; ++c) {
        const int nloc = (wv << 4) + (c << 3) + g;
        const bool act = (nloc < ncnt);
        const int node = nbase + nloc;
        const int start = act ? rp_s[nloc] : 0;
        const int end = act ? rp_s[nloc + 1] : 0;
        h8v acc0 = {0, 0, 0, 0, 0, 0, 0, 0};
        h8v acc1 = {0, 0, 0, 0, 0, 0, 0, 0};
        if (act) acc0 = *(const h8v*)&hs[(size_t)node * 64 + fb];  // self row
        if (inlds) {
            int j = start - seg0;
            const int e_ = end - seg0;
            for (; j + 1 < e_; j += 2) {
                int s0 = csr_s[j], s1 = csr_s[j + 1];
                acc0 += *(const h8v*)&hs[(size_t)s0 * 64 + fb];
                acc1 += *(const h8v*)&hs[(size_t)s1 * 64 + fb];
            }
            if (j < e_) acc0 += *(const h8v*)&hs[(size_t)csr_s[j] * 64 + fb];
        } else {
            int j = start;
            for (; j + 1 < end; j += 2) {
                int s0 = nt_ld_i(&csr[j]), s1 = nt_ld_i(&csr[j + 1]);
                acc0 += *(const h8v*)&hs[(size_t)s0 * 64 + fb];
                acc1 += *(const h8v*)&hs[(size_t)s1 * 64 + fb];
            }
            if (j < end) acc0 += *(const h8v*)&hs[(size_t)nt_ld_i(&csr[j]) * 64 + fb];
        }
        if (act) {
            const float dn = dinv_s[nloc];
            float4 bb0 = *(const float4*)&b1[fb];
            float4 bb1 = *(const float4*)&b1[fb + 4];
            float4 r0, r1;
            r0.x = fmaxf(dn * ((float)acc0[0] + (float)acc1[0]) + bb0.x, 0.f);
            r0.y = fmaxf(dn * ((float)acc0[1] + (float)acc1[1]) + bb0.y, 0.f);
            r0.z = fmaxf(dn * ((float)acc0[2] + (float)acc1[2]) + bb0.z, 0.f);
            r0.w = fmaxf(dn * ((float)acc0[3] + (float)acc1[3]) + bb0.w, 0.f);
            r1.x = fmaxf(dn * ((float)acc0[4] + (float)acc1[4]) + bb1.x, 0.f);
            r1.y = fmaxf(dn * ((float)acc0[5] + (float)acc1[5]) + bb1.y, 0.f);
            r1.z = fmaxf(dn * ((float)acc0[6] + (float)acc1[6]) + bb1.z, 0.f);
            r1.w = fmaxf(dn * ((float)acc0[7] + (float)acc1[7]) + bb1.w, 0.f);
            *(float4*)&rowbuf[wv][g][fb] = r0;
            *(float4*)&rowbuf[wv][g][fb + 4] = r1;
        }
        // GEMM2: same-wave LDS dep (in-order DS per wave); 4 cols per lane, K=64
        if (act) {
            float a0 = 0.f, a1 = 0.f, a2 = 0.f, a3 = 0.f;
            const int cb = fl << 2;
#pragma unroll
            for (int k = 0; k < 64; ++k) {
                float r = rowbuf[wv][g][k];
                a0 += r * w2s[k][cb + 0];
                a1 += r * w2s[k][cb + 1];
                a2 += r * w2s[k][cb + 2];
                a3 += r * w2s[k][cb + 3];
            }
            const float dn = dinv_s[nloc];
            h4v hv;
            hv.x = (_Float16)(dn * a0);
            hv.y = (_Float16)(dn * a1);
            hv.z = (_Float16)(dn * a2);
            hv.w = (_Float16)(dn * a3);
            *(h4v*)&h2s[(size_t)node * 32 + cb] = hv;
        }
    }
}

// ---------------- layer-2 agg (group-per-node): 16 groups x 4 lanes ----------------
// each 4-lane group owns one node, lanes cover the 64B fp16 row -> 16 rows in
// flight per wave load-step; no reduce; direct fp32 epilogue to out.
__global__ __launch_bounds__(THREADS) void k_agg2(const int* __restrict__ row_ptr,
                                                  const int* __restrict__ csr,
                                                  const float* __restrict__ dinv,
                                                  const _Float16* __restrict__ hs,
                                                  const float* __restrict__ b2,
                                                  float* __restrict__ out, int N) {
    __shared__ int rp_s[AGG_NODES + 1];
    __shared__ float dinv_s[AGG_NODES];
    __shared__ int csr_s[CSR_LDS];
    const int tid = threadIdx.x;
    const int nbase = blockIdx.x * AGG_NODES;
    const int nend = min(nbase + AGG_NODES, N);
    const int ncnt = nend - nbase;
    if (tid <= ncnt) rp_s[tid] = row_ptr[nbase + tid];
    if (tid < ncnt) dinv_s[tid] = dinv[nbase + tid];
    __syncthreads();
    const int seg0 = rp_s[0];
    const int seglen = rp_s[ncnt] - seg0;
    const bool inlds = (seglen <= CSR_LDS);
    if (inlds)
        for (int t = tid; t < seglen; t += THREADS) csr_s[t] = nt_ld_i(&csr[seg0 + t]);
    __syncthreads();

    const int wv = tid >> 6, lane = tid & 63;
    const int g = lane >> 2, fl = lane & 3;
    const int fb = fl << 3;

    const int nloc = (wv << 4) + g;
    const bool act = (nloc < ncnt);
    const int node = nbase + nloc;
    const int start = act ? rp_s[nloc] : 0;
    const int end = act ? rp_s[nloc + 1] : 0;
    h8v acc0 = {0, 0, 0, 0, 0, 0, 0, 0};
    h8v acc1 = {0, 0, 0, 0, 0, 0, 0, 0};
    if (act) acc0 = *(const h8v*)&hs[(size_t)node * 32 + fb];  // self row
    if (inlds) {
        int j = start - seg0;
        const int e_ = end - seg0;
        for (; j + 1 < e_; j += 2) {
            int s0 = csr_s[j], s1 = csr_s[j + 1];
            acc0 += *(const h8v*)&hs[(size_t)s0 * 32 + fb];
            acc1 += *(const h8v*)&hs[(size_t)s1 * 32 + fb];
        }
        if (j < e_) acc0 += *(const h8v*)&hs[(size_t)csr_s[j] * 32 + fb];
    } else {
        int j = start;
        for (; j + 1 < end; j += 2) {
            int s0 = nt_ld_i(&csr[j]), s1 = nt_ld_i(&csr[j + 1]);
            acc0 += *(const h8v*)&hs[(size_t)s0 * 32 + fb];
            acc1 += *(const h8v*)&hs[(size_t)s1 * 32 + fb];
        }
        if (j < end) acc0 += *(const h8v*)&hs[(size_t)nt_ld_i(&csr[j]) * 32 + fb];
    }
    if (act) {
        const float dn = dinv_s[nloc];
        float4 bb0 = *(const float4*)&b2[fb];
        float4 bb1 = *(const float4*)&b2[fb + 4];
        float4 r0, r1;
        r0.x = dn * ((float)acc0[0] + (float)acc1[0]) + bb0.x;
        r0.y = dn * ((float)acc0[1] + (float)acc1[1]) + bb0.y;
        r0.z = dn * ((float)acc0[2] + (float)acc1[2]) + bb0.z;
        r0.w = dn * ((float)acc0[3] + (float)acc1[3]) + bb0.w;
        r1.x = dn * ((float)acc0[4] + (float)acc1[4]) + bb1.x;
        r1.y = dn * ((float)acc0[5] + (float)acc1[5]) + bb1.y;
        r1.z = dn * ((float)acc0[6] + (float)acc1[6]) + bb1.z;
        r1.w = dn * ((float)acc0[7] + (float)acc1[7]) + bb1.w;
        *(float4*)&out[(size_t)node * 32 + fb] = r0;
        *(float4*)&out[(size_t)node * 32 + fb + 4] = r1;
    }
}

extern "C" void kernel_launch(void* const* d_in, const int* in_sizes, int n_in,
                              void* d_out, int out_size, void* d_ws, size_t ws_size,
                              hipStream_t stream) {
    const int N = in_sizes[0] / 128;
    const int E = in_sizes[1] / 2;
    const float* x  = (const float*)d_in[0];
    const int*   ei = (const int*)d_in[1];
    const float* W1 = (const float*)d_in[2];
    const float* b1 = (const float*)d_in[3];
    const float* W2 = (const float*)d_in[4];
    const float* b2 = (const float*)d_in[5];
    float* out = (float*)d_out;

    const int NB = (N + 255) >> BSHIFT;

    // workspace carve. pairs aliases h1b (dead until k_gemm1, which runs after k_sort;
    // E*4B = 6.4MB <= N*64*2B = 12.8MB).
    float*     dinv    = (float*)d_ws;                    // N
    _Float16*  h1b     = (_Float16*)(dinv + N);           // N*64 fp16
    _Float16*  h2b     = h1b + (size_t)N * 64;            // N*32 fp16
    int*       csr_src = (int*)(h2b + (size_t)N * 32);    // E
    int*       row_ptr = csr_src + E;                     // N+1
    int*       bh      = row_ptr + N + 1;                 // PBLK*NB
    int*       bbase   = bh + (size_t)PBLK * NB;          // PBLK*NB
    int*       bcnt    = bbase + (size_t)PBLK * NB;       // NB
    int*       boff    = bcnt + NB;                       // NB+1
    unsigned*  pairs   = (unsigned*)h1b;                  // E (aliased)

    k_hist<<<PBLK, HTHREADS, (NB + 1) * 4, stream>>>(ei, E, bh, NB);
    k_colsum<<<NB, THREADS, 0, stream>>>(bh, bcnt, NB);
    k_scan<<<1, THREADS, 0, stream>>>(bcnt, boff, NB);
    k_bbase<<<NB, 64, 0, stream>>>(bh, boff, bbase, NB);
    k_partition<<<PBLK, HTHREADS, (2 * NB + 1) * 4, stream>>>(ei, E, bbase, pairs, NB);
    k_sort<<<NB, THREADS, 0, stream>>>(pairs, boff, csr_src, row_ptr, dinv, N, NB);

    k_gemm1<<<(N + 63) / 64, THREADS, 0, stream>>>(x, W1, dinv, h1b, N);
    const int ablk = (N + AGG_NODES - 1) / AGG_NODES;
    k_agg1f<<<ablk, THREADS, 0, stream>>>(row_ptr, csr_src, dinv, h1b, b1, W2, h2b, N);
    k_agg2<<<ablk, THREADS, 0, stream>>>(row_ptr, csr_src, dinv, h2b, b2, out, N);
}

// Round 11
// 128.133 us; speedup vs baseline: 5.4716x; 1.1008x over previous
//
#include <hip/hip_runtime.h>
#include <math.h>

// GCN 2-layer. Radix-partition CSR build; group-per-node gather aggregation
// (block-staged CSR, fp16 rows, packed accumulate); GEMM1 on MFMA
// (fp16 inputs, fp32 accumulate); layer-1 agg fused with ReLU + GEMM2.
// out = Anorm( relu(Anorm(x@W1)+b1) @ W2 ) + b2,  Anorm = D^-1/2 (A+I) D^-1/2.

#define THREADS 256
#define HTHREADS 512  // hist/partition blocks
#define PBLK 256      // partition blocks (hist chunking; k_colsum assumes ==THREADS)
#define BSHIFT 8      // bucket = dst >> 8 (256 nodes/bucket)
#define AGG_NODES 64  // nodes per aggregation block
#define CSR_LDS 2048  // staged csr entries budget (mean 1024)

typedef _Float16 h8v __attribute__((ext_vector_type(8)));
typedef _Float16 h4v __attribute__((ext_vector_type(4)));
typedef float f32x4 __attribute__((ext_vector_type(4)));

__device__ __forceinline__ int nt_ld_i(const int* p) {
    return __builtin_nontemporal_load(p);
}

// block-local int64-layout detection (consistent across blocks: same data)
__device__ __forceinline__ int detect64_block(const int* __restrict__ idx, int E,
                                              int* s_flag) {
    if (threadIdx.x == 0) *s_flag = 1;
    __syncthreads();
    int n = (E < 1024) ? E : 1024;
    for (int i = threadIdx.x; i < n; i += blockDim.x)
        if (idx[2 * i + 1] != 0) *s_flag = 0;  // benign race, only 0 written
    __syncthreads();
    return *s_flag;
}

// ---------------- per-block bucket histogram (+ inline detection) ----------------
__global__ __launch_bounds__(HTHREADS) void k_hist(const int* __restrict__ idx, int E,
                                                   int* __restrict__ bh, int NB) {
    extern __shared__ int lh[];  // NB + 1
    int is64 = detect64_block(idx, E, &lh[NB]);
    for (int t = threadIdx.x; t < NB; t += HTHREADS) lh[t] = 0;
    __syncthreads();
    int chunk = (E + PBLK - 1) / PBLK;
    int start = blockIdx.x * chunk;
    int end = min(start + chunk, E);
    for (int e = start + threadIdx.x; e < end; e += HTHREADS) {
        int d = is64 ? idx[2 * E + 2 * e] : idx[E + e];
        atomicAdd(&lh[d >> BSHIFT], 1);
    }
    __syncthreads();
    for (int t = threadIdx.x; t < NB; t += HTHREADS)
        bh[blockIdx.x * NB + t] = lh[t];
}

// ---------------- bucket totals: one block per bucket ----------------
__global__ __launch_bounds__(THREADS) void k_colsum(const int* __restrict__ bh,
                                                    int* __restrict__ bcnt, int NB) {
    __shared__ int ws[4];
    int b = blockIdx.x;
    int v = bh[threadIdx.x * NB + b];  // PBLK == THREADS
    int lane = threadIdx.x & 63, w = threadIdx.x >> 6;
#pragma unroll
    for (int o = 32; o; o >>= 1) v += __shfl_down(v, o);
    if (lane == 0) ws[w] = v;
    __syncthreads();
    if (threadIdx.x == 0) bcnt[b] = ws[0] + ws[1] + ws[2] + ws[3];
}

// ---------------- exclusive scan of bucket totals (1 block) ----------------
__global__ __launch_bounds__(THREADS) void k_scan(const int* __restrict__ cnt,
                                                  int* __restrict__ off, int NB) {
    __shared__ int wsum[4];
    __shared__ int carry_s;
    if (threadIdx.x == 0) carry_s = 0;
    __syncthreads();
    int t = threadIdx.x, lane = t & 63, w = t >> 6;
    for (int base = 0; base < NB; base += THREADS) {
        int i = base + t;
        int raw = (i < NB) ? cnt[i] : 0;
        int v = raw;
#pragma unroll
        for (int o = 1; o < 64; o <<= 1) {
            int u = __shfl_up(v, o);
            if (lane >= o) v += u;
        }
        if (lane == 63) wsum[w] = v;
        __syncthreads();
        int c0 = carry_s;
        int wadd = 0;
#pragma unroll
        for (int k = 0; k < 4; ++k) if (k < w) wadd += wsum[k];
        if (i < NB) off[i] = v - raw + wadd + c0;
        __syncthreads();
        if (t == 0) carry_s += wsum[0] + wsum[1] + wsum[2] + wsum[3];
        __syncthreads();
    }
    if (t == 0) off[NB] = carry_s;  // == E
}

// ---------------- per-(block,bucket) bases: one wave per bucket ----------------
__global__ __launch_bounds__(64) void k_bbase(const int* __restrict__ bh,
                                              const int* __restrict__ boff,
                                              int* __restrict__ bbase, int NB) {
    int b = blockIdx.x;
    int lane = threadIdx.x;
    int carry = boff[b];
    for (int base = 0; base < PBLK; base += 64) {
        int idx = (base + lane) * NB + b;
        int raw = bh[idx];
        int v = raw;
#pragma unroll
        for (int o = 1; o < 64; o <<= 1) {
            int u = __shfl_up(v, o);
            if (lane >= o) v += u;
        }
        bbase[idx] = carry + v - raw;
        carry += __shfl(v, 63);
    }
}

// ---------------- partition: packed (ldst<<24)|src into bucket ranges ----------------
// requires src < 2^24 (N = 100K here)
__global__ __launch_bounds__(HTHREADS) void k_partition(const int* __restrict__ idx, int E,
                                                        const int* __restrict__ bbase,
                                                        unsigned* __restrict__ pairs, int NB) {
    extern __shared__ int sm[];
    int* lbase = sm;        // NB
    int* lcur  = sm + NB;   // NB (+1 for flag)
    int is64 = detect64_block(idx, E, &lcur[NB]);
    for (int t = threadIdx.x; t < NB; t += HTHREADS) {
        lbase[t] = bbase[blockIdx.x * NB + t];
        lcur[t] = 0;
    }
    __syncthreads();
    int chunk = (E + PBLK - 1) / PBLK;
    int start = blockIdx.x * chunk;
    int end = min(start + chunk, E);
    for (int e = start + threadIdx.x; e < end; e += HTHREADS) {
        int s = is64 ? idx[2 * e] : idx[e];
        int d = is64 ? idx[2 * E + 2 * e] : idx[E + e];
        int b = d >> BSHIFT;
        int r = atomicAdd(&lcur[b], 1);
        pairs[lbase[b] + r] = (unsigned)s | ((unsigned)(d & 255) << 24);
    }
}

// ---------------- per-bucket counting sort -> csr_src, row_ptr, dinv ----------------
__global__ __launch_bounds__(THREADS) void k_sort(const unsigned* __restrict__ pairs,
                                                  const int* __restrict__ boff,
                                                  int* __restrict__ csr_src,
                                                  int* __restrict__ row_ptr,
                                                  float* __restrict__ dinv, int N, int NB) {
    __shared__ int cnt[256];
    __shared__ int cur[256];
    __shared__ int wsum[4];
    const int b = blockIdx.x, t = threadIdx.x;
    const int start = boff[b], end = boff[b + 1];
    cnt[t] = 0;
    __syncthreads();
    for (int j = start + t; j < end; j += THREADS)
        atomicAdd(&cnt[pairs[j] >> 24], 1);
    __syncthreads();
    int deg = cnt[t];
    int lane = t & 63, w = t >> 6;
    int v = deg;
#pragma unroll
    for (int o = 1; o < 64; o <<= 1) {
        int u = __shfl_up(v, o);
        if (lane >= o) v += u;
    }
    if (lane == 63) wsum[w] = v;
    __syncthreads();
    int wadd = 0;
#pragma unroll
    for (int k = 0; k < 4; ++k) if (k < w) wadd += wsum[k];
    int pos = start + (v - deg) + wadd;
    cur[t] = pos;
    int node = (b << BSHIFT) + t;
    if (node < N) {
        row_ptr[node] = pos;
        dinv[node] = rsqrtf((float)(deg + 1));  // +1 self loop
    }
    if (b == NB - 1 && t == 0) row_ptr[N] = end;
    __syncthreads();
    for (int j = start + t; j < end; j += THREADS) {
        unsigned p = pairs[j];
        int r = atomicAdd(&cur[p >> 24], 1);
        csr_src[r] = (int)(p & 0xFFFFFFu);
    }
}

// ---------------- GEMM1 (MFMA): h1h = fp16(dinv[row] * (x @ W1)) ----------------
// [N,128]@[128,64] fp16-in fp32-acc. Block 64 rows x 64 cols, 4 waves; wave =
// one 16-row band. A-frag: row=lane&15, k=(lane>>4)*8+i (contig from xs);
// B-frag: col=lane&15, k likewise (contig from transposed wsT);
// C/D: col=lane&15, row=(lane>>4)*4+reg  [verified m89 mapping].
__global__ __launch_bounds__(THREADS) void k_gemm1(const float* __restrict__ x,
                                                   const float* __restrict__ W,
                                                   const float* __restrict__ dinv,
                                                   _Float16* __restrict__ h, int N) {
    __shared__ _Float16 xs[64][136];   // [row][k], +8 pad (17.4KB)
    __shared__ _Float16 wsT[64][136];  // [col][k], transposed W1 (17.4KB)
    const int tid = threadIdx.x;
    const int brow = blockIdx.x * 64;
    // stage x -> fp16 (coalesced float4 reads, 8B LDS writes)
    for (int f = tid; f < 64 * 32; f += THREADS) {
        int r = f >> 5, c4 = (f & 31) << 2;
        int row = brow + r;
        float4 v = make_float4(0.f, 0.f, 0.f, 0.f);
        if (row < N) v = *(const float4*)&x[(size_t)row * 128 + c4];
        h4v hv;
        hv.x = (_Float16)v.x; hv.y = (_Float16)v.y;
        hv.z = (_Float16)v.z; hv.w = (_Float16)v.w;
        *(h4v*)&xs[r][c4] = hv;
    }
    // stage W1 transposed -> fp16 (coalesced reads, scalar scatter writes)
    for (int f = tid; f < 128 * 16; f += THREADS) {
        int k = f >> 4, n4 = (f & 15) << 2;
        float4 w = *(const float4*)&W[(size_t)k * 64 + n4];
        wsT[n4 + 0][k] = (_Float16)w.x;
        wsT[n4 + 1][k] = (_Float16)w.y;
        wsT[n4 + 2][k] = (_Float16)w.z;
        wsT[n4 + 3][k] = (_Float16)w.w;
    }
    __syncthreads();
    const int wv = tid >> 6, lane = tid & 63;
    const int fr = lane & 15;   // A row / B col / C col within tile
    const int kg = lane >> 4;   // k-group
    f32x4 acc[4];
    acc[0] = acc[1] = acc[2] = acc[3] = (f32x4){0.f, 0.f, 0.f, 0.f};
#pragma unroll
    for (int ks = 0; ks < 4; ++ks) {
        h8v a = *(const h8v*)&xs[(wv << 4) + fr][(kg << 3) + (ks << 5)];
#pragma unroll
        for (int c = 0; c < 4; ++c) {
            h8v b = *(const h8v*)&wsT[(c << 4) + fr][(kg << 3) + (ks << 5)];
            acc[c] = __builtin_amdgcn_mfma_f32_16x16x32_f16(a, b, acc[c], 0, 0, 0);
        }
    }
#pragma unroll
    for (int i = 0; i < 4; ++i) {
        int row = brow + (wv << 4) + (kg << 2) + i;
        if (row < N) {
            float dn = dinv[row];
#pragma unroll
            for (int c = 0; c < 4; ++c)
                h[(size_t)row * 64 + (c << 4) + fr] = (_Float16)(acc[c][i] * dn);
        }
    }
}

// ---------------- fused layer-1 agg + bias + ReLU + GEMM2 (group-per-node) ----------------
__global__ __launch_bounds__(THREADS) void k_agg1f(const int* __restrict__ row_ptr,
                                                   const int* __restrict__ csr,
                                                   const float* __restrict__ dinv,
                                                   const _Float16* __restrict__ hs,
                                                   const float* __restrict__ b1,
                                                   const float* __restrict__ W2,
                                                   _Float16* __restrict__ h2s, int N) {
    __shared__ float w2s[64][32];          // 8KB
    __shared__ float rowbuf[4][8][68];     // 8.5KB, padded
    __shared__ int rp_s[AGG_NODES + 1];
    __shared__ float dinv_s[AGG_NODES];
    __shared__ int csr_s[CSR_LDS];         // 8KB
    const int tid = threadIdx.x;
    for (int f = tid; f < 64 * 8; f += THREADS) {
        int k = f >> 3, c4 = (f & 7) << 2;
        *(float4*)&w2s[k][c4] = *(const float4*)&W2[(size_t)k * 32 + c4];
    }
    const int nbase = blockIdx.x * AGG_NODES;
    const int nend = min(nbase + AGG_NODES, N);
    const int ncnt = nend - nbase;
    if (tid <= ncnt) rp_s[tid] = row_ptr[nbase + tid];
    if (tid < ncnt) dinv_s[tid] = dinv[nbase + tid];
    __syncthreads();
    const int seg0 = rp_s[0];
    const int seglen = rp_s[ncnt] - seg0;
    const bool inlds = (seglen <= CSR_LDS);
    if (inlds)
        for (int t = tid; t < seglen; t += THREADS) csr_s[t] = nt_ld_i(&csr[seg0 + t]);
    __syncthreads();

    const int wv = tid >> 6, lane = tid & 63;
    const int g = lane >> 3, fl = lane & 7;
    const int fb = fl << 3;

    for (int c = 0; c < 2; ++c) {
        const int nloc = (wv << 4) + (c << 3) + g;
        const bool act = (nloc < ncnt);
        const int node = nbase + nloc;
        const int start = act ? rp_s[nloc] : 0;
        const int end = act ? rp_s[nloc + 1] : 0;
        h8v acc0 = {0, 0, 0, 0, 0, 0, 0, 0};
        h8v acc1 = {0, 0, 0, 0, 0, 0, 0, 0};
        if (act) acc0 = *(const h8v*)&hs[(size_t)node * 64 + fb];  // self row
        if (inlds) {
            int j = start - seg0;
            const int e_ = end - seg0;
            for (; j + 1 < e_; j += 2) {
                int s0 = csr_s[j], s1 = csr_s[j + 1];
                acc0 += *(const h8v*)&hs[(size_t)s0 * 64 + fb];
                acc1 += *(const h8v*)&hs[(size_t)s1 * 64 + fb];
            }
            if (j < e_) acc0 += *(const h8v*)&hs[(size_t)csr_s[j] * 64 + fb];
        } else {
            int j = start;
            for (; j + 1 < end; j += 2) {
                int s0 = nt_ld_i(&csr[j]), s1 = nt_ld_i(&csr[j + 1]);
                acc0 += *(const h8v*)&hs[(size_t)s0 * 64 + fb];
                acc1 += *(const h8v*)&hs[(size_t)s1 * 64 + fb];
            }
            if (j < end) acc0 += *(const h8v*)&hs[(size_t)nt_ld_i(&csr[j]) * 64 + fb];
        }
        if (act) {
            const float dn = dinv_s[nloc];
            float4 bb0 = *(const float4*)&b1[fb];
            float4 bb1 = *(const float4*)&b1[fb + 4];
            float4 r0, r1;
            r0.x = fmaxf(dn * ((float)acc0[0] + (float)acc1[0]) + bb0.x, 0.f);
            r0.y = fmaxf(dn * ((float)acc0[1] + (float)acc1[1]) + bb0.y, 0.f);
            r0.z = fmaxf(dn * ((float)acc0[2] + (float)acc1[2]) + bb0.z, 0.f);
            r0.w = fmaxf(dn * ((float)acc0[3] + (float)acc1[3]) + bb0.w, 0.f);
            r1.x = fmaxf(dn * ((float)acc0[4] + (float)acc1[4]) + bb1.x, 0.f);
            r1.y = fmaxf(dn * ((float)acc0[5] + (float)acc1[5]) + bb1.y, 0.f);
            r1.z = fmaxf(dn * ((float)acc0[6] + (float)acc1[6]) + bb1.z, 0.f);
            r1.w = fmaxf(dn * ((float)acc0[7] + (float)acc1[7]) + bb1.w, 0.f);
            *(float4*)&rowbuf[wv][g][fb] = r0;
            *(float4*)&rowbuf[wv][g][fb + 4] = r1;
        }
        if (act) {
            float a0 = 0.f, a1 = 0.f, a2 = 0.f, a3 = 0.f;
            const int cb = fl << 2;
#pragma unroll
            for (int k = 0; k < 64; ++k) {
                float r = rowbuf[wv][g][k];
                a0 += r * w2s[k][cb + 0];
                a1 += r * w2s[k][cb + 1];
                a2 += r * w2s[k][cb + 2];
                a3 += r * w2s[k][cb + 3];
            }
            const float dn = dinv_s[nloc];
            h4v hv;
            hv.x = (_Float16)(dn * a0);
            hv.y = (_Float16)(dn * a1);
            hv.z = (_Float16)(dn * a2);
            hv.w = (_Float16)(dn * a3);
            *(h4v*)&h2s[(size_t)node * 32 + cb] = hv;
        }
    }
}

// ---------------- layer-2 agg (group-per-node): 16 groups x 4 lanes ----------------
__global__ __launch_bounds__(THREADS) void k_agg2(const int* __restrict__ row_ptr,
                                                  const int* __restrict__ csr,
                                                  const float* __restrict__ dinv,
                                                  const _Float16* __restrict__ hs,
                                                  const float* __restrict__ b2,
                                                  float* __restrict__ out, int N) {
    __shared__ int rp_s[AGG_NODES + 1];
    __shared__ float dinv_s[AGG_NODES];
    __shared__ int csr_s[CSR_LDS];
    const int tid = threadIdx.x;
    const int nbase = blockIdx.x * AGG_NODES;
    const int nend = min(nbase + AGG_NODES, N);
    const int ncnt = nend - nbase;
    if (tid <= ncnt) rp_s[tid] = row_ptr[nbase + tid];
    if (tid < ncnt) dinv_s[tid] = dinv[nbase + tid];
    __syncthreads();
    const int seg0 = rp_s[0];
    const int seglen = rp_s[ncnt] - seg0;
    const bool inlds = (seglen <= CSR_LDS);
    if (inlds)
        for (int t = tid; t < seglen; t += THREADS) csr_s[t] = nt_ld_i(&csr[seg0 + t]);
    __syncthreads();

    const int wv = tid >> 6, lane = tid & 63;
    const int g = lane >> 2, fl = lane & 3;
    const int fb = fl << 3;

    const int nloc = (wv << 4) + g;
    const bool act = (nloc < ncnt);
    const int node = nbase + nloc;
    const int start = act ? rp_s[nloc] : 0;
    const int end = act ? rp_s[nloc + 1] : 0;
    h8v acc0 = {0, 0, 0, 0, 0, 0, 0, 0};
    h8v acc1 = {0, 0, 0, 0, 0, 0, 0, 0};
    if (act) acc0 = *(const h8v*)&hs[(size_t)node * 32 + fb];  // self row
    if (inlds) {
        int j = start - seg0;
        const int e_ = end - seg0;
        for (; j + 1 < e_; j += 2) {
            int s0 = csr_s[j], s1 = csr_s[j + 1];
            acc0 += *(const h8v*)&hs[(size_t)s0 * 32 + fb];
            acc1 += *(const h8v*)&hs[(size_t)s1 * 32 + fb];
        }
        if (j < e_) acc0 += *(const h8v*)&hs[(size_t)csr_s[j] * 32 + fb];
    } else {
        int j = start;
        for (; j + 1 < end; j += 2) {
            int s0 = nt_ld_i(&csr[j]), s1 = nt_ld_i(&csr[j + 1]);
            acc0 += *(const h8v*)&hs[(size_t)s0 * 32 + fb];
            acc1 += *(const h8v*)&hs[(size_t)s1 * 32 + fb];
        }
        if (j < end) acc0 += *(const h8v*)&hs[(size_t)nt_ld_i(&csr[j]) * 32 + fb];
    }
    if (act) {
        const float dn = dinv_s[nloc];
        float4 bb0 = *(const float4*)&b2[fb];
        float4 bb1 = *(const float4*)&b2[fb + 4];
        float4 r0, r1;
        r0.x = dn * ((float)acc0[0] + (float)acc1[0]) + bb0.x;
        r0.y = dn * ((float)acc0[1] + (float)acc1[1]) + bb0.y;
        r0.z = dn * ((float)acc0[2] + (float)acc1[2]) + bb0.z;
        r0.w = dn * ((float)acc0[3] + (float)acc1[3]) + bb0.w;
        r1.x = dn * ((float)acc0[4] + (float)acc1[4]) + bb1.x;
        r1.y = dn * ((float)acc0[5] + (float)acc1[5]) + bb1.y;
        r1.z = dn * ((float)acc0[6] + (float)acc1[6]) + bb1.z;
        r1.w = dn * ((float)acc0[7] + (float)acc1[7]) + bb1.w;
        *(float4*)&out[(size_t)node * 32 + fb] = r0;
        *(float4*)&out[(size_t)node * 32 + fb + 4] = r1;
    }
}

extern "C" void kernel_launch(void* const* d_in, const int* in_sizes, int n_in,
                              void* d_out, int out_size, void* d_ws, size_t ws_size,
                              hipStream_t stream) {
    const int N = in_sizes[0] / 128;
    const int E = in_sizes[1] / 2;
    const float* x  = (const float*)d_in[0];
    const int*   ei = (const int*)d_in[1];
    const float* W1 = (const float*)d_in[2];
    const float* b1 = (const float*)d_in[3];
    const float* W2 = (const float*)d_in[4];
    const float* b2 = (const float*)d_in[5];
    float* out = (float*)d_out;

    const int NB = (N + 255) >> BSHIFT;

    // workspace carve. pairs aliases h1b (dead until k_gemm1, which runs after k_sort;
    // E*4B = 6.4MB <= N*64*2B = 12.8MB).
    float*     dinv    = (float*)d_ws;                    // N
    _Float16*  h1b     = (_Float16*)(dinv + N);           // N*64 fp16
    _Float16*  h2b     = h1b + (size_t)N * 64;            // N*32 fp16
    int*       csr_src = (int*)(h2b + (size_t)N * 32);    // E
    int*       row_ptr = csr_src + E;                     // N+1
    int*       bh      = row_ptr + N + 1;                 // PBLK*NB
    int*       bbase   = bh + (size_t)PBLK * NB;          // PBLK*NB
    int*       bcnt    = bbase + (size_t)PBLK * NB;       // NB
    int*       boff    = bcnt + NB;                       // NB+1
    unsigned*  pairs   = (unsigned*)h1b;                  // E (aliased)

    k_hist<<<PBLK, HTHREADS, (NB + 1) * 4, stream>>>(ei, E, bh, NB);
    k_colsum<<<NB, THREADS, 0, stream>>>(bh, bcnt, NB);
    k_scan<<<1, THREADS, 0, stream>>>(bcnt, boff, NB);
    k_bbase<<<NB, 64, 0, stream>>>(bh, boff, bbase, NB);
    k_partition<<<PBLK, HTHREADS, (2 * NB + 1) * 4, stream>>>(ei, E, bbase, pairs, NB);
    k_sort<<<NB, THREADS, 0, stream>>>(pairs, boff, csr_src, row_ptr, dinv, N, NB);

    k_gemm1<<<(N + 63) / 64, THREADS, 0, stream>>>(x, W1, dinv, h1b, N);
    const int ablk = (N + AGG_NODES - 1) / AGG_NODES;
    k_agg1f<<<ablk, THREADS, 0, stream>>>(row_ptr, csr_src, dinv, h1b, b1, W2, h2b, N);
    k_agg2<<<ablk, THREADS, 0, stream>>>(row_ptr, csr_src, dinv, h2b, b2, out, N);
}

// Round 12
// 126.019 us; speedup vs baseline: 5.5634x; 1.0168x over previous
//
#include <hip/hip_runtime.h>
#include <math.h>

// GCN 2-layer. Radix-partition CSR build; group-per-node gather aggregation
// (block-staged CSR, fp16 rows, 4-deep unrolled packed accumulate); GEMM1 on
// MFMA (fp16 in, fp32 acc); layer-1 agg fused with ReLU + GEMM2 (vectorized).
// out = Anorm( relu(Anorm(x@W1)+b1) @ W2 ) + b2,  Anorm = D^-1/2 (A+I) D^-1/2.

#define THREADS 256
#define HTHREADS 512  // hist/partition block size
#define PBLK 512      // partition blocks (hist chunking; k_colsum sums 2 rows/thread)
#define BSHIFT 8      // bucket = dst >> 8 (256 nodes/bucket)
#define AGG_NODES 64  // nodes per aggregation block
#define CSR_LDS 1536  // staged csr entries budget (mean 1024, sigma 32)

typedef _Float16 h8v __attribute__((ext_vector_type(8)));
typedef _Float16 h4v __attribute__((ext_vector_type(4)));
typedef float f32x4 __attribute__((ext_vector_type(4)));

__device__ __forceinline__ int nt_ld_i(const int* p) {
    return __builtin_nontemporal_load(p);
}

// block-local int64-layout detection (consistent across blocks: same data)
__device__ __forceinline__ int detect64_block(const int* __restrict__ idx, int E,
                                              int* s_flag) {
    if (threadIdx.x == 0) *s_flag = 1;
    __syncthreads();
    int n = (E < 1024) ? E : 1024;
    for (int i = threadIdx.x; i < n; i += blockDim.x)
        if (idx[2 * i + 1] != 0) *s_flag = 0;  // benign race, only 0 written
    __syncthreads();
    return *s_flag;
}

// ---------------- per-block bucket histogram (+ inline detection) ----------------
__global__ __launch_bounds__(HTHREADS) void k_hist(const int* __restrict__ idx, int E,
                                                   int* __restrict__ bh, int NB) {
    extern __shared__ int lh[];  // NB + 1
    int is64 = detect64_block(idx, E, &lh[NB]);
    for (int t = threadIdx.x; t < NB; t += HTHREADS) lh[t] = 0;
    __syncthreads();
    int chunk = (E + PBLK - 1) / PBLK;
    int start = blockIdx.x * chunk;
    int end = min(start + chunk, E);
    for (int e = start + threadIdx.x; e < end; e += HTHREADS) {
        int d = is64 ? idx[2 * E + 2 * e] : idx[E + e];
        atomicAdd(&lh[d >> BSHIFT], 1);
    }
    __syncthreads();
    for (int t = threadIdx.x; t < NB; t += HTHREADS)
        bh[blockIdx.x * NB + t] = lh[t];
}

// ---------------- bucket totals: one block per bucket (PBLK = 2*THREADS) ----------------
__global__ __launch_bounds__(THREADS) void k_colsum(const int* __restrict__ bh,
                                                    int* __restrict__ bcnt, int NB) {
    __shared__ int ws[4];
    int b = blockIdx.x;
    int v = bh[threadIdx.x * NB + b] + bh[(threadIdx.x + THREADS) * NB + b];
    int lane = threadIdx.x & 63, w = threadIdx.x >> 6;
#pragma unroll
    for (int o = 32; o; o >>= 1) v += __shfl_down(v, o);
    if (lane == 0) ws[w] = v;
    __syncthreads();
    if (threadIdx.x == 0) bcnt[b] = ws[0] + ws[1] + ws[2] + ws[3];
}

// ---------------- exclusive scan of bucket totals (1 block) ----------------
__global__ __launch_bounds__(THREADS) void k_scan(const int* __restrict__ cnt,
                                                  int* __restrict__ off, int NB) {
    __shared__ int wsum[4];
    __shared__ int carry_s;
    if (threadIdx.x == 0) carry_s = 0;
    __syncthreads();
    int t = threadIdx.x, lane = t & 63, w = t >> 6;
    for (int base = 0; base < NB; base += THREADS) {
        int i = base + t;
        int raw = (i < NB) ? cnt[i] : 0;
        int v = raw;
#pragma unroll
        for (int o = 1; o < 64; o <<= 1) {
            int u = __shfl_up(v, o);
            if (lane >= o) v += u;
        }
        if (lane == 63) wsum[w] = v;
        __syncthreads();
        int c0 = carry_s;
        int wadd = 0;
#pragma unroll
        for (int k = 0; k < 4; ++k) if (k < w) wadd += wsum[k];
        if (i < NB) off[i] = v - raw + wadd + c0;
        __syncthreads();
        if (t == 0) carry_s += wsum[0] + wsum[1] + wsum[2] + wsum[3];
        __syncthreads();
    }
    if (t == 0) off[NB] = carry_s;  // == E
}

// ---------------- per-(block,bucket) bases: one wave per bucket ----------------
__global__ __launch_bounds__(64) void k_bbase(const int* __restrict__ bh,
                                              const int* __restrict__ boff,
                                              int* __restrict__ bbase, int NB) {
    int b = blockIdx.x;
    int lane = threadIdx.x;
    int carry = boff[b];
    for (int base = 0; base < PBLK; base += 64) {
        int idx = (base + lane) * NB + b;
        int raw = bh[idx];
        int v = raw;
#pragma unroll
        for (int o = 1; o < 64; o <<= 1) {
            int u = __shfl_up(v, o);
            if (lane >= o) v += u;
        }
        bbase[idx] = carry + v - raw;
        carry += __shfl(v, 63);
    }
}

// ---------------- partition: packed (ldst<<24)|src into bucket ranges ----------------
// requires src < 2^24 (N = 100K here)
__global__ __launch_bounds__(HTHREADS) void k_partition(const int* __restrict__ idx, int E,
                                                        const int* __restrict__ bbase,
                                                        unsigned* __restrict__ pairs, int NB) {
    extern __shared__ int sm[];
    int* lbase = sm;        // NB
    int* lcur  = sm + NB;   // NB (+1 for flag)
    int is64 = detect64_block(idx, E, &lcur[NB]);
    for (int t = threadIdx.x; t < NB; t += HTHREADS) {
        lbase[t] = bbase[blockIdx.x * NB + t];
        lcur[t] = 0;
    }
    __syncthreads();
    int chunk = (E + PBLK - 1) / PBLK;
    int start = blockIdx.x * chunk;
    int end = min(start + chunk, E);
    for (int e = start + threadIdx.x; e < end; e += HTHREADS) {
        int s = is64 ? idx[2 * e] : idx[e];
        int d = is64 ? idx[2 * E + 2 * e] : idx[E + e];
        int b = d >> BSHIFT;
        int r = atomicAdd(&lcur[b], 1);
        pairs[lbase[b] + r] = (unsigned)s | ((unsigned)(d & 255) << 24);
    }
}

// ---------------- per-bucket counting sort -> csr_src, row_ptr, dinv ----------------
__global__ __launch_bounds__(THREADS) void k_sort(const unsigned* __restrict__ pairs,
                                                  const int* __restrict__ boff,
                                                  int* __restrict__ csr_src,
                                                  int* __restrict__ row_ptr,
                                                  float* __restrict__ dinv, int N, int NB) {
    __shared__ int cnt[256];
    __shared__ int cur[256];
    __shared__ int wsum[4];
    const int b = blockIdx.x, t = threadIdx.x;
    const int start = boff[b], end = boff[b + 1];
    cnt[t] = 0;
    __syncthreads();
    for (int j = start + t; j < end; j += THREADS)
        atomicAdd(&cnt[pairs[j] >> 24], 1);
    __syncthreads();
    int deg = cnt[t];
    int lane = t & 63, w = t >> 6;
    int v = deg;
#pragma unroll
    for (int o = 1; o < 64; o <<= 1) {
        int u = __shfl_up(v, o);
        if (lane >= o) v += u;
    }
    if (lane == 63) wsum[w] = v;
    __syncthreads();
    int wadd = 0;
#pragma unroll
    for (int k = 0; k < 4; ++k) if (k < w) wadd += wsum[k];
    int pos = start + (v - deg) + wadd;
    cur[t] = pos;
    int node = (b << BSHIFT) + t;
    if (node < N) {
        row_ptr[node] = pos;
        dinv[node] = rsqrtf((float)(deg + 1));  // +1 self loop
    }
    if (b == NB - 1 && t == 0) row_ptr[N] = end;
    __syncthreads();
    for (int j = start + t; j < end; j += THREADS) {
        unsigned p = pairs[j];
        int r = atomicAdd(&cur[p >> 24], 1);
        csr_src[r] = (int)(p & 0xFFFFFFu);
    }
}

// ---------------- GEMM1 (MFMA): h1h = fp16(dinv[row] * (x @ W1)) ----------------
__global__ __launch_bounds__(THREADS) void k_gemm1(const float* __restrict__ x,
                                                   const float* __restrict__ W,
                                                   const float* __restrict__ dinv,
                                                   _Float16* __restrict__ h, int N) {
    __shared__ _Float16 xs[64][136];   // [row][k], +8 pad
    __shared__ _Float16 wsT[64][136];  // [col][k], transposed W1
    const int tid = threadIdx.x;
    const int brow = blockIdx.x * 64;
    for (int f = tid; f < 64 * 32; f += THREADS) {
        int r = f >> 5, c4 = (f & 31) << 2;
        int row = brow + r;
        float4 v = make_float4(0.f, 0.f, 0.f, 0.f);
        if (row < N) v = *(const float4*)&x[(size_t)row * 128 + c4];
        h4v hv;
        hv.x = (_Float16)v.x; hv.y = (_Float16)v.y;
        hv.z = (_Float16)v.z; hv.w = (_Float16)v.w;
        *(h4v*)&xs[r][c4] = hv;
    }
    for (int f = tid; f < 128 * 16; f += THREADS) {
        int k = f >> 4, n4 = (f & 15) << 2;
        float4 w = *(const float4*)&W[(size_t)k * 64 + n4];
        wsT[n4 + 0][k] = (_Float16)w.x;
        wsT[n4 + 1][k] = (_Float16)w.y;
        wsT[n4 + 2][k] = (_Float16)w.z;
        wsT[n4 + 3][k] = (_Float16)w.w;
    }
    __syncthreads();
    const int wv = tid >> 6, lane = tid & 63;
    const int fr = lane & 15;
    const int kg = lane >> 4;
    f32x4 acc[4];
    acc[0] = acc[1] = acc[2] = acc[3] = (f32x4){0.f, 0.f, 0.f, 0.f};
#pragma unroll
    for (int ks = 0; ks < 4; ++ks) {
        h8v a = *(const h8v*)&xs[(wv << 4) + fr][(kg << 3) + (ks << 5)];
#pragma unroll
        for (int c = 0; c < 4; ++c) {
            h8v b = *(const h8v*)&wsT[(c << 4) + fr][(kg << 3) + (ks << 5)];
            acc[c] = __builtin_amdgcn_mfma_f32_16x16x32_f16(a, b, acc[c], 0, 0, 0);
        }
    }
#pragma unroll
    for (int i = 0; i < 4; ++i) {
        int row = brow + (wv << 4) + (kg << 2) + i;
        if (row < N) {
            float dn = dinv[row];
#pragma unroll
            for (int c = 0; c < 4; ++c)
                h[(size_t)row * 64 + (c << 4) + fr] = (_Float16)(acc[c][i] * dn);
        }
    }
}

// ---------------- fused layer-1 agg + bias + ReLU + GEMM2 (group-per-node, unroll-4) ----------------
__global__ __launch_bounds__(THREADS) void k_agg1f(const int* __restrict__ row_ptr,
                                                   const int* __restrict__ csr,
                                                   const float* __restrict__ dinv,
                                                   const _Float16* __restrict__ hs,
                                                   const float* __restrict__ b1,
                                                   const float* __restrict__ W2,
                                                   _Float16* __restrict__ h2s, int N) {
    __shared__ float w2s[64][32];          // 8KB
    __shared__ float rowbuf[4][8][68];     // 8.5KB, padded
    __shared__ int rp_s[AGG_NODES + 1];
    __shared__ float dinv_s[AGG_NODES];
    __shared__ int csr_s[CSR_LDS];         // 6KB
    const int tid = threadIdx.x;
    for (int f = tid; f < 64 * 8; f += THREADS) {
        int k = f >> 3, c4 = (f & 7) << 2;
        *(float4*)&w2s[k][c4] = *(const float4*)&W2[(size_t)k * 32 + c4];
    }
    const int nbase = blockIdx.x * AGG_NODES;
    const int nend = min(nbase + AGG_NODES, N);
    const int ncnt = nend - nbase;
    if (tid <= ncnt) rp_s[tid] = row_ptr[nbase + tid];
    if (tid < ncnt) dinv_s[tid] = dinv[nbase + tid];
    __syncthreads();
    const int seg0 = rp_s[0];
    const int seglen = rp_s[ncnt] - seg0;
    const bool inlds = (seglen <= CSR_LDS);
    if (inlds)
        for (int t = tid; t < seglen; t += THREADS) csr_s[t] = nt_ld_i(&csr[seg0 + t]);
    __syncthreads();

    const int wv = tid >> 6, lane = tid & 63;
    const int g = lane >> 3, fl = lane & 7;
    const int fb = fl << 3;

    for (int c = 0; c < 2; ++c) {
        const int nloc = (wv << 4) + (c << 3) + g;
        const bool act = (nloc < ncnt);
        const int node = nbase + nloc;
        const int start = act ? rp_s[nloc] : 0;
        const int end = act ? rp_s[nloc + 1] : 0;
        h8v a0 = {0, 0, 0, 0, 0, 0, 0, 0};
        h8v a1 = a0, a2 = a0, a3 = a0;
        if (act) a0 = *(const h8v*)&hs[(size_t)node * 64 + fb];  // self row
        if (inlds) {
            int j = start - seg0;
            const int e_ = end - seg0;
            for (; j + 3 < e_; j += 4) {
                int s0 = csr_s[j], s1 = csr_s[j + 1], s2 = csr_s[j + 2], s3 = csr_s[j + 3];
                a0 += *(const h8v*)&hs[(size_t)s0 * 64 + fb];
                a1 += *(const h8v*)&hs[(size_t)s1 * 64 + fb];
                a2 += *(const h8v*)&hs[(size_t)s2 * 64 + fb];
                a3 += *(const h8v*)&hs[(size_t)s3 * 64 + fb];
            }
            int rem = e_ - j;
            if (rem > 0) a1 += *(const h8v*)&hs[(size_t)csr_s[j] * 64 + fb];
            if (rem > 1) a2 += *(const h8v*)&hs[(size_t)csr_s[j + 1] * 64 + fb];
            if (rem > 2) a3 += *(const h8v*)&hs[(size_t)csr_s[j + 2] * 64 + fb];
        } else {
            int j = start;
            for (; j + 3 < end; j += 4) {
                int s0 = nt_ld_i(&csr[j]), s1 = nt_ld_i(&csr[j + 1]);
                int s2 = nt_ld_i(&csr[j + 2]), s3 = nt_ld_i(&csr[j + 3]);
                a0 += *(const h8v*)&hs[(size_t)s0 * 64 + fb];
                a1 += *(const h8v*)&hs[(size_t)s1 * 64 + fb];
                a2 += *(const h8v*)&hs[(size_t)s2 * 64 + fb];
                a3 += *(const h8v*)&hs[(size_t)s3 * 64 + fb];
            }
            int rem = end - j;
            if (rem > 0) a1 += *(const h8v*)&hs[(size_t)nt_ld_i(&csr[j]) * 64 + fb];
            if (rem > 1) a2 += *(const h8v*)&hs[(size_t)nt_ld_i(&csr[j + 1]) * 64 + fb];
            if (rem > 2) a3 += *(const h8v*)&hs[(size_t)nt_ld_i(&csr[j + 2]) * 64 + fb];
        }
        if (act) {
            const float dn = dinv_s[nloc];
            float4 bb0 = *(const float4*)&b1[fb];
            float4 bb1 = *(const float4*)&b1[fb + 4];
            float4 r0, r1;
            r0.x = fmaxf(dn * (((float)a0[0] + (float)a1[0]) + ((float)a2[0] + (float)a3[0])) + bb0.x, 0.f);
            r0.y = fmaxf(dn * (((float)a0[1] + (float)a1[1]) + ((float)a2[1] + (float)a3[1])) + bb0.y, 0.f);
            r0.z = fmaxf(dn * (((float)a0[2] + (float)a1[2]) + ((float)a2[2] + (float)a3[2])) + bb0.z, 0.f);
            r0.w = fmaxf(dn * (((float)a0[3] + (float)a1[3]) + ((float)a2[3] + (float)a3[3])) + bb0.w, 0.f);
            r1.x = fmaxf(dn * (((float)a0[4] + (float)a1[4]) + ((float)a2[4] + (float)a3[4])) + bb1.x, 0.f);
            r1.y = fmaxf(dn * (((float)a0[5] + (float)a1[5]) + ((float)a2[5] + (float)a3[5])) + bb1.y, 0.f);
            r1.z = fmaxf(dn * (((float)a0[6] + (float)a1[6]) + ((float)a2[6] + (float)a3[6])) + bb1.z, 0.f);
            r1.w = fmaxf(dn * (((float)a0[7] + (float)a1[7]) + ((float)a2[7] + (float)a3[7])) + bb1.w, 0.f);
            *(float4*)&rowbuf[wv][g][fb] = r0;
            *(float4*)&rowbuf[wv][g][fb + 4] = r1;
        }
        // GEMM2 (vectorized): 4 cols/lane, K=64 in float4 steps
        if (act) {
            float c0 = 0.f, c1 = 0.f, c2 = 0.f, c3 = 0.f;
            const int cb = fl << 2;
#pragma unroll
            for (int k4 = 0; k4 < 64; k4 += 4) {
                float4 r = *(const float4*)&rowbuf[wv][g][k4];
                float4 w0 = *(const float4*)&w2s[k4 + 0][cb];
                float4 w1 = *(const float4*)&w2s[k4 + 1][cb];
                float4 w2 = *(const float4*)&w2s[k4 + 2][cb];
                float4 w3 = *(const float4*)&w2s[k4 + 3][cb];
                c0 += r.x * w0.x + r.y * w1.x + r.z * w2.x + r.w * w3.x;
                c1 += r.x * w0.y + r.y * w1.y + r.z * w2.y + r.w * w3.y;
                c2 += r.x * w0.z + r.y * w1.z + r.z * w2.z + r.w * w3.z;
                c3 += r.x * w0.w + r.y * w1.w + r.z * w2.w + r.w * w3.w;
            }
            const float dn = dinv_s[nloc];
            h4v hv;
            hv.x = (_Float16)(dn * c0);
            hv.y = (_Float16)(dn * c1);
            hv.z = (_Float16)(dn * c2);
            hv.w = (_Float16)(dn * c3);
            *(h4v*)&h2s[(size_t)node * 32 + (fl << 2)] = hv;
        }
    }
}

// ---------------- layer-2 agg (group-per-node, unroll-4): 16 groups x 4 lanes ----------------
__global__ __launch_bounds__(THREADS) void k_agg2(const int* __restrict__ row_ptr,
                                                  const int* __restrict__ csr,
                                                  const float* __restrict__ dinv,
                                                  const _Float16* __restrict__ hs,
                                                  const float* __restrict__ b2,
                                                  float* __restrict__ out, int N) {
    __shared__ int rp_s[AGG_NODES + 1];
    __shared__ float dinv_s[AGG_NODES];
    __shared__ int csr_s[CSR_LDS];
    const int tid = threadIdx.x;
    const int nbase = blockIdx.x * AGG_NODES;
    const int nend = min(nbase + AGG_NODES, N);
    const int ncnt = nend - nbase;
    if (tid <= ncnt) rp_s[tid] = row_ptr[nbase + tid];
    if (tid < ncnt) dinv_s[tid] = dinv[nbase + tid];
    __syncthreads();
    const int seg0 = rp_s[0];
    const int seglen = rp_s[ncnt] - seg0;
    const bool inlds = (seglen <= CSR_LDS);
    if (inlds)
        for (int t = tid; t < seglen; t += THREADS) csr_s[t] = nt_ld_i(&csr[seg0 + t]);
    __syncthreads();

    const int wv = tid >> 6, lane = tid & 63;
    const int g = lane >> 2, fl = lane & 3;
    const int fb = fl << 3;

    const int nloc = (wv << 4) + g;
    const bool act = (nloc < ncnt);
    const int node = nbase + nloc;
    const int start = act ? rp_s[nloc] : 0;
    const int end = act ? rp_s[nloc + 1] : 0;
    h8v a0 = {0, 0, 0, 0, 0, 0, 0, 0};
    h8v a1 = a0, a2 = a0, a3 = a0;
    if (act) a0 = *(const h8v*)&hs[(size_t)node * 32 + fb];  // self row
    if (inlds) {
        int j = start - seg0;
        const int e_ = end - seg0;
        for (; j + 3 < e_; j += 4) {
            int s0 = csr_s[j], s1 = csr_s[j + 1], s2 = csr_s[j + 2], s3 = csr_s[j + 3];
            a0 += *(const h8v*)&hs[(size_t)s0 * 32 + fb];
            a1 += *(const h8v*)&hs[(size_t)s1 * 32 + fb];
            a2 += *(const h8v*)&hs[(size_t)s2 * 32 + fb];
            a3 += *(const h8v*)&hs[(size_t)s3 * 32 + fb];
        }
        int rem = e_ - j;
        if (rem > 0) a1 += *(const h8v*)&hs[(size_t)csr_s[j] * 32 + fb];
        if (rem > 1) a2 += *(const h8v*)&hs[(size_t)csr_s[j + 1] * 32 + fb];
        if (rem > 2) a3 += *(const h8v*)&hs[(size_t)csr_s[j + 2] * 32 + fb];
    } else {
        int j = start;
        for (; j + 3 < end; j += 4) {
            int s0 = nt_ld_i(&csr[j]), s1 = nt_ld_i(&csr[j + 1]);
            int s2 = nt_ld_i(&csr[j + 2]), s3 = nt_ld_i(&csr[j + 3]);
            a0 += *(const h8v*)&hs[(size_t)s0 * 32 + fb];
            a1 += *(const h8v*)&hs[(size_t)s1 * 32 + fb];
            a2 += *(const h8v*)&hs[(size_t)s2 * 32 + fb];
            a3 += *(const h8v*)&hs[(size_t)s3 * 32 + fb];
        }
        int rem = end - j;
        if (rem > 0) a1 += *(const h8v*)&hs[(size_t)nt_ld_i(&csr[j]) * 32 + fb];
        if (rem > 1) a2 += *(const h8v*)&hs[(size_t)nt_ld_i(&csr[j + 1]) * 32 + fb];
        if (rem > 2) a3 += *(const h8v*)&hs[(size_t)nt_ld_i(&csr[j + 2]) * 32 + fb];
    }
    if (act) {
        const float dn = dinv_s[nloc];
        float4 bb0 = *(const float4*)&b2[fb];
        float4 bb1 = *(const float4*)&b2[fb + 4];
        float4 r0, r1;
        r0.x = dn * (((float)a0[0] + (float)a1[0]) + ((float)a2[0] + (float)a3[0])) + bb0.x;
        r0.y = dn * (((float)a0[1] + (float)a1[1]) + ((float)a2[1] + (float)a3[1])) + bb0.y;
        r0.z = dn * (((float)a0[2] + (float)a1[2]) + ((float)a2[2] + (float)a3[2])) + bb0.z;
        r0.w = dn * (((float)a0[3] + (float)a1[3]) + ((float)a2[3] + (float)a3[3])) + bb0.w;
        r1.x = dn * (((float)a0[4] + (float)a1[4]) + ((float)a2[4] + (float)a3[4])) + bb1.x;
        r1.y = dn * (((float)a0[5] + (float)a1[5]) + ((float)a2[5] + (float)a3[5])) + bb1.y;
        r1.z = dn * (((float)a0[6] + (float)a1[6]) + ((float)a2[6] + (float)a3[6])) + bb1.z;
        r1.w = dn * (((float)a0[7] + (float)a1[7]) + ((float)a2[7] + (float)a3[7])) + bb1.w;
        *(float4*)&out[(size_t)node * 32 + fb] = r0;
        *(float4*)&out[(size_t)node * 32 + fb + 4] = r1;
    }
}

extern "C" void kernel_launch(void* const* d_in, const int* in_sizes, int n_in,
                              void* d_out, int out_size, void* d_ws, size_t ws_size,
                              hipStream_t stream) {
    const int N = in_sizes[0] / 128;
    const int E = in_sizes[1] / 2;
    const float* x  = (const float*)d_in[0];
    const int*   ei = (const int*)d_in[1];
    const float* W1 = (const float*)d_in[2];
    const float* b1 = (const float*)d_in[3];
    const float* W2 = (const float*)d_in[4];
    const float* b2 = (const float*)d_in[5];
    float* out = (float*)d_out;

    const int NB = (N + 255) >> BSHIFT;

    // workspace carve. pairs aliases h1b (dead until k_gemm1, which runs after k_sort;
    // E*4B = 6.4MB <= N*64*2B = 12.8MB).
    float*     dinv    = (float*)d_ws;                    // N
    _Float16*  h1b     = (_Float16*)(dinv + N);           // N*64 fp16
    _Float16*  h2b     = h1b + (size_t)N * 64;            // N*32 fp16
    int*       csr_src = (int*)(h2b + (size_t)N * 32);    // E
    int*       row_ptr = csr_src + E;                     // N+1
    int*       bh      = row_ptr + N + 1;                 // PBLK*NB
    int*       bbase   = bh + (size_t)PBLK * NB;          // PBLK*NB
    int*       bcnt    = bbase + (size_t)PBLK * NB;       // NB
    int*       boff    = bcnt + NB;                       // NB+1
    unsigned*  pairs   = (unsigned*)h1b;                  // E (aliased)

    k_hist<<<PBLK, HTHREADS, (NB + 1) * 4, stream>>>(ei, E, bh, NB);
    k_colsum<<<NB, THREADS, 0, stream>>>(bh, bcnt, NB);
    k_scan<<<1, THREADS, 0, stream>>>(bcnt, boff, NB);
    k_bbase<<<NB, 64, 0, stream>>>(bh, boff, bbase, NB);
    k_partition<<<PBLK, HTHREADS, (2 * NB + 1) * 4, stream>>>(ei, E, bbase, pairs, NB);
    k_sort<<<NB, THREADS, 0, stream>>>(pairs, boff, csr_src, row_ptr, dinv, N, NB);

    k_gemm1<<<(N + 63) / 64, THREADS, 0, stream>>>(x, W1, dinv, h1b, N);
    const int ablk = (N + AGG_NODES - 1) / AGG_NODES;
    k_agg1f<<<ablk, THREADS, 0, stream>>>(row_ptr, csr_src, dinv, h1b, b1, W2, h2b, N);
    k_agg2<<<ablk, THREADS, 0, stream>>>(row_ptr, csr_src, dinv, h2b, b2, out, N);
}